// Round 1
// baseline (321.608 us; speedup 1.0000x reference)
//
#include <hip/hip_runtime.h>
#include <hip/hip_bf16.h>

#define BB 8
#define TT 12
#define NN 512
#define DD 64
#define RTOT (BB*TT*NN)   // 49152 rows
#define EPSF 1e-5f

// ---------------------------------------------------------------------------
// GEMM: Y[r][e] = sum_d X[r][d] * W[d][e] + bias[e]
// one thread per row, W staged in LDS (broadcast reads), 128 rows/block
// ---------------------------------------------------------------------------
__global__ __launch_bounds__(128) void gemm_bias(const float* __restrict__ X,
                                                 const float* __restrict__ W,
                                                 const float* __restrict__ bias,
                                                 float* __restrict__ Y) {
    __shared__ float Wl[4096];
    int tid = threadIdx.x;
    for (int i = tid; i < 1024; i += 128)
        ((float4*)Wl)[i] = ((const float4*)W)[i];
    __syncthreads();

    int row = blockIdx.x * 128 + tid;
    float x[64];
    const float4* xr = (const float4*)(X + (size_t)row * 64);
#pragma unroll
    for (int i = 0; i < 16; i++) {
        float4 t = xr[i];
        x[4*i] = t.x; x[4*i+1] = t.y; x[4*i+2] = t.z; x[4*i+3] = t.w;
    }
    float4* yo = (float4*)(Y + (size_t)row * 64);
#pragma unroll
    for (int ec = 0; ec < 4; ec++) {
        float acc[16];
#pragma unroll
        for (int j = 0; j < 16; j++) acc[j] = bias[ec*16 + j];
#pragma unroll 8
        for (int d = 0; d < 64; d++) {
            float xv = x[d];
            const float4* wr = (const float4*)&Wl[d*64 + ec*16];
            float4 w0 = wr[0], w1 = wr[1], w2 = wr[2], w3 = wr[3];
            acc[0]  += xv*w0.x; acc[1]  += xv*w0.y; acc[2]  += xv*w0.z; acc[3]  += xv*w0.w;
            acc[4]  += xv*w1.x; acc[5]  += xv*w1.y; acc[6]  += xv*w1.z; acc[7]  += xv*w1.w;
            acc[8]  += xv*w2.x; acc[9]  += xv*w2.y; acc[10] += xv*w2.z; acc[11] += xv*w2.w;
            acc[12] += xv*w3.x; acc[13] += xv*w3.y; acc[14] += xv*w3.z; acc[15] += xv*w3.w;
        }
        yo[ec*4+0] = make_float4(acc[0],  acc[1],  acc[2],  acc[3]);
        yo[ec*4+1] = make_float4(acc[4],  acc[5],  acc[6],  acc[7]);
        yo[ec*4+2] = make_float4(acc[8],  acc[9],  acc[10], acc[11]);
        yo[ec*4+3] = make_float4(acc[12], acc[13], acc[14], acc[15]);
    }
}

// ---------------------------------------------------------------------------
// per-channel sum / sumsq partials -> global atomicAdd into st[0:64], st[64:128]
// ---------------------------------------------------------------------------
__global__ __launch_bounds__(256) void stats_kernel(const float* __restrict__ Y,
                                                    float* __restrict__ st) {
    __shared__ float red[512];
    int tid = threadIdx.x;
    int c = tid & 63;
    int g = tid >> 6;
    float sum = 0.f, ssq = 0.f;
    for (int r = blockIdx.x * 4 + g; r < RTOT; r += gridDim.x * 4) {
        float v = Y[(size_t)r * 64 + c];
        sum += v; ssq += v * v;
    }
    red[tid] = sum; red[256 + tid] = ssq;
    __syncthreads();
    if (tid < 64) {
        float s = red[tid] + red[tid+64] + red[tid+128] + red[tid+192];
        float q = red[256+tid] + red[256+tid+64] + red[256+tid+128] + red[256+tid+192];
        atomicAdd(&st[tid], s);
        atomicAdd(&st[64 + tid], q);
    }
}

// coef[c] = g*rsqrt(var+eps); coef[64+c] = beta - mean*coef[c]
__global__ void finalize_k(const float* __restrict__ st, const float* __restrict__ g,
                           const float* __restrict__ be, float* __restrict__ coef) {
    int c = threadIdx.x;
    float inv = 1.f / (float)RTOT;
    float mean = st[c] * inv;
    float var  = st[64 + c] * inv - mean * mean;
    float a = g[c] * rsqrtf(var + EPSF);
    coef[c] = a;
    coef[64 + c] = be[c] - mean * a;
}

// ---------------------------------------------------------------------------
// attention: one block per (head h, b*T+t). K,V (BN+ReLU applied) in LDS.
// Each thread owns 2 query rows; no-max softmax (scores >= 0, bounded).
// Masked query row (mask chunk sums to 0): zero q -> uniform softmax -> mean(V),
// exactly matching the -1e9 fill semantics.
// ---------------------------------------------------------------------------
__global__ __launch_bounds__(256) void attn_kernel(
        const float* __restrict__ Yq, const float* __restrict__ Yk,
        const float* __restrict__ Yv, const float* __restrict__ mask,
        const float* __restrict__ cq, const float* __restrict__ ck,
        const float* __restrict__ cv, float* __restrict__ O) {
    __shared__ float kl[512][8];
    __shared__ float vl[512][8];
    int p = blockIdx.x;
    int h = p / 96;              // B*T = 96
    int bt = p - h * 96;
    int row0 = bt * 512;
    int co = h * 8;
    int tid = threadIdx.x;

    for (int i = tid; i < 4096; i += 256) {
        int m = i >> 3, c = i & 7, cc = co + c;
        size_t idx = (size_t)(row0 + m) * 64 + cc;
        kl[m][c] = fmaxf(ck[cc] * Yk[idx] + ck[64 + cc], 0.f);
        vl[m][c] = fmaxf(cv[cc] * Yv[idx] + cv[64 + cc], 0.f);
    }
    __syncthreads();

    const float SC = 0.35355339059327373f * 1.4426950408889634f; // 1/sqrt(8)*log2(e)
    int n0 = tid, n1 = tid + 256;
    float q0[8], q1[8];
    float mr0 = 0.f, mr1 = 0.f;
#pragma unroll
    for (int c = 0; c < 8; c++) {
        int cc = co + c;
        float a = cq[cc], b = cq[64 + cc];
        q0[c] = fmaxf(a * Yq[(size_t)(row0 + n0) * 64 + cc] + b, 0.f) * SC;
        q1[c] = fmaxf(a * Yq[(size_t)(row0 + n1) * 64 + cc] + b, 0.f) * SC;
        mr0 += mask[(size_t)(row0 + n0) * 64 + cc];
        mr1 += mask[(size_t)(row0 + n1) * 64 + cc];
    }
    if (mr0 == 0.f) {
#pragma unroll
        for (int c = 0; c < 8; c++) q0[c] = 0.f;
    }
    if (mr1 == 0.f) {
#pragma unroll
        for (int c = 0; c < 8; c++) q1[c] = 0.f;
    }

    float l0 = 0.f, l1 = 0.f;
    float a0[8] = {0.f,0.f,0.f,0.f,0.f,0.f,0.f,0.f};
    float a1[8] = {0.f,0.f,0.f,0.f,0.f,0.f,0.f,0.f};
    for (int m = 0; m < 512; m++) {
        float4 k0 = *(const float4*)&kl[m][0];
        float4 k4 = *(const float4*)&kl[m][4];
        float s0 = q0[0]*k0.x + q0[1]*k0.y + q0[2]*k0.z + q0[3]*k0.w
                 + q0[4]*k4.x + q0[5]*k4.y + q0[6]*k4.z + q0[7]*k4.w;
        float s1 = q1[0]*k0.x + q1[1]*k0.y + q1[2]*k0.z + q1[3]*k0.w
                 + q1[4]*k4.x + q1[5]*k4.y + q1[6]*k4.z + q1[7]*k4.w;
        float p0 = __builtin_amdgcn_exp2f(s0);
        float p1 = __builtin_amdgcn_exp2f(s1);
        l0 += p0; l1 += p1;
        float4 v0 = *(const float4*)&vl[m][0];
        float4 v4 = *(const float4*)&vl[m][4];
        a0[0] += p0*v0.x; a0[1] += p0*v0.y; a0[2] += p0*v0.z; a0[3] += p0*v0.w;
        a0[4] += p0*v4.x; a0[5] += p0*v4.y; a0[6] += p0*v4.z; a0[7] += p0*v4.w;
        a1[0] += p1*v0.x; a1[1] += p1*v0.y; a1[2] += p1*v0.z; a1[3] += p1*v0.w;
        a1[4] += p1*v4.x; a1[5] += p1*v4.y; a1[6] += p1*v4.z; a1[7] += p1*v4.w;
    }
    float r0 = 1.f / l0, r1 = 1.f / l1;
    float4* o0 = (float4*)&O[(size_t)(row0 + n0) * 64 + co];
    float4* o1 = (float4*)&O[(size_t)(row0 + n1) * 64 + co];
    o0[0] = make_float4(a0[0]*r0, a0[1]*r0, a0[2]*r0, a0[3]*r0);
    o0[1] = make_float4(a0[4]*r0, a0[5]*r0, a0[6]*r0, a0[7]*r0);
    o1[0] = make_float4(a1[0]*r1, a1[1]*r1, a1[2]*r1, a1[3]*r1);
    o1[1] = make_float4(a1[4]*r1, a1[5]*r1, a1[6]*r1, a1[7]*r1);
}

// out = relu(a*y + b), float4-vectorized
__global__ __launch_bounds__(256) void norm_relu(const float* __restrict__ Y,
                                                 const float* __restrict__ coef,
                                                 float* __restrict__ out) {
    int i = blockIdx.x * 256 + threadIdx.x;   // over RTOT*64/4 float4s
    float4 y = ((const float4*)Y)[i];
    int cb = (i & 15) * 4;
    float4 o;
    o.x = fmaxf(coef[cb+0]*y.x + coef[64+cb+0], 0.f);
    o.y = fmaxf(coef[cb+1]*y.y + coef[64+cb+1], 0.f);
    o.z = fmaxf(coef[cb+2]*y.z + coef[64+cb+2], 0.f);
    o.w = fmaxf(coef[cb+3]*y.w + coef[64+cb+3], 0.f);
    ((float4*)out)[i] = o;
}

extern "C" void kernel_launch(void* const* d_in, const int* in_sizes, int n_in,
                              void* d_out, int out_size, void* d_ws, size_t ws_size,
                              hipStream_t stream) {
    const float* Q    = (const float*)d_in[0];
    const float* Kin  = (const float*)d_in[1];
    const float* mask = (const float*)d_in[2];
    // d_in[3] = batch_size scalar (unused; compile-time constant)
    const float* Wq = (const float*)d_in[4];
    const float* bq = (const float*)d_in[5];
    const float* gq = (const float*)d_in[6];
    const float* betaq = (const float*)d_in[7];
    const float* Wk = (const float*)d_in[8];
    const float* bk = (const float*)d_in[9];
    const float* gk = (const float*)d_in[10];
    const float* betak = (const float*)d_in[11];
    const float* Wv = (const float*)d_in[12];
    const float* bv = (const float*)d_in[13];
    const float* gv = (const float*)d_in[14];
    const float* betav = (const float*)d_in[15];
    const float* Wo = (const float*)d_in[16];
    const float* bo = (const float*)d_in[17];
    const float* go = (const float*)d_in[18];
    const float* betao = (const float*)d_in[19];

    float* ws   = (float*)d_ws;
    const size_t TSZ = (size_t)RTOT * 64;   // 3,145,728 floats
    float* Y0   = ws;              // Yq, later reused as Yo
    float* Y1   = ws + TSZ;        // Yk
    float* Y2   = ws + 2 * TSZ;    // Yv
    float* Obuf = ws + 3 * TSZ;    // merged attention output
    float* stats = ws + 4 * TSZ;   // 4 x 128 floats (sum, sumsq)
    float* coef  = stats + 512;    // 4 x 128 floats (a, b)

    hipMemsetAsync(stats, 0, 512 * sizeof(float), stream);

    gemm_bias<<<RTOT/128, 128, 0, stream>>>(Q,   Wq, bq, Y0);
    gemm_bias<<<RTOT/128, 128, 0, stream>>>(Kin, Wk, bk, Y1);
    gemm_bias<<<RTOT/128, 128, 0, stream>>>(Kin, Wv, bv, Y2);

    stats_kernel<<<192, 256, 0, stream>>>(Y0, stats + 0);
    stats_kernel<<<192, 256, 0, stream>>>(Y1, stats + 128);
    stats_kernel<<<192, 256, 0, stream>>>(Y2, stats + 256);

    finalize_k<<<1, 64, 0, stream>>>(stats + 0,   gq, betaq, coef + 0);
    finalize_k<<<1, 64, 0, stream>>>(stats + 128, gk, betak, coef + 128);
    finalize_k<<<1, 64, 0, stream>>>(stats + 256, gv, betav, coef + 256);

    attn_kernel<<<768, 256, 0, stream>>>(Y0, Y1, Y2, mask,
                                         coef + 0, coef + 128, coef + 256, Obuf);

    gemm_bias<<<RTOT/128, 128, 0, stream>>>(Obuf, Wo, bo, Y0);   // Yo into Y0
    stats_kernel<<<192, 256, 0, stream>>>(Y0, stats + 384);
    finalize_k<<<1, 64, 0, stream>>>(stats + 384, go, betao, coef + 384);

    norm_relu<<<(RTOT*64/4)/256, 256, 0, stream>>>(Y0, coef + 384, (float*)d_out);
}

// Round 3
// 306.961 us; speedup vs baseline: 1.0477x; 1.0477x over previous
//
#include <hip/hip_runtime.h>
#include <hip/hip_bf16.h>

#define BB 8
#define TT 12
#define NN 512
#define DD 64
#define RTOT (BB*TT*NN)   // 49152 rows
#define EPSF 1e-5f

typedef _Float16 h2 __attribute__((ext_vector_type(2)));

__device__ __forceinline__ h2 cvt2h(float a, float b) {
    return __builtin_bit_cast(h2, __builtin_amdgcn_cvt_pkrtz(a, b));
}
__device__ __forceinline__ h2 bch2(unsigned int u) { return __builtin_bit_cast(h2, u); }
__device__ __forceinline__ unsigned int bcu(h2 v) { return __builtin_bit_cast(unsigned int, v); }

#if __has_builtin(__builtin_amdgcn_fdot2)
__device__ __forceinline__ float fdot2f(h2 a, h2 b, float c) {
    return __builtin_amdgcn_fdot2(a, b, c, false);
}
#else
__device__ __forceinline__ float fdot2f(h2 a, h2 b, float c) {
    return c + (float)a[0] * (float)b[0] + (float)a[1] * (float)b[1];
}
#endif

// ---------------------------------------------------------------------------
// GEMM: Y[r][e] = sum_d X[r][d] * W[d][e] + bias[e]
// ---------------------------------------------------------------------------
__global__ __launch_bounds__(128) void gemm_bias(const float* __restrict__ X,
                                                 const float* __restrict__ W,
                                                 const float* __restrict__ bias,
                                                 float* __restrict__ Y) {
    __shared__ float Wl[4096];
    int tid = threadIdx.x;
    for (int i = tid; i < 1024; i += 128)
        ((float4*)Wl)[i] = ((const float4*)W)[i];
    __syncthreads();

    int row = blockIdx.x * 128 + tid;
    float x[64];
    const float4* xr = (const float4*)(X + (size_t)row * 64);
#pragma unroll
    for (int i = 0; i < 16; i++) {
        float4 t = xr[i];
        x[4*i] = t.x; x[4*i+1] = t.y; x[4*i+2] = t.z; x[4*i+3] = t.w;
    }
    float4* yo = (float4*)(Y + (size_t)row * 64);
#pragma unroll
    for (int ec = 0; ec < 4; ec++) {
        float acc[16];
#pragma unroll
        for (int j = 0; j < 16; j++) acc[j] = bias[ec*16 + j];
#pragma unroll 8
        for (int d = 0; d < 64; d++) {
            float xv = x[d];
            const float4* wr = (const float4*)&Wl[d*64 + ec*16];
            float4 w0 = wr[0], w1 = wr[1], w2 = wr[2], w3 = wr[3];
            acc[0]  += xv*w0.x; acc[1]  += xv*w0.y; acc[2]  += xv*w0.z; acc[3]  += xv*w0.w;
            acc[4]  += xv*w1.x; acc[5]  += xv*w1.y; acc[6]  += xv*w1.z; acc[7]  += xv*w1.w;
            acc[8]  += xv*w2.x; acc[9]  += xv*w2.y; acc[10] += xv*w2.z; acc[11] += xv*w2.w;
            acc[12] += xv*w3.x; acc[13] += xv*w3.y; acc[14] += xv*w3.z; acc[15] += xv*w3.w;
        }
        yo[ec*4+0] = make_float4(acc[0],  acc[1],  acc[2],  acc[3]);
        yo[ec*4+1] = make_float4(acc[4],  acc[5],  acc[6],  acc[7]);
        yo[ec*4+2] = make_float4(acc[8],  acc[9],  acc[10], acc[11]);
        yo[ec*4+3] = make_float4(acc[12], acc[13], acc[14], acc[15]);
    }
}

// ---------------------------------------------------------------------------
// per-channel sum / sumsq partials -> atomicAdd into st[0:64], st[64:128]
// ---------------------------------------------------------------------------
__global__ __launch_bounds__(256) void stats_kernel(const float* __restrict__ Y,
                                                    float* __restrict__ st) {
    __shared__ float red[512];
    int tid = threadIdx.x;
    int c = tid & 63;
    int g = tid >> 6;
    float sum = 0.f, ssq = 0.f;
    for (int r = blockIdx.x * 4 + g; r < RTOT; r += gridDim.x * 4) {
        float v = Y[(size_t)r * 64 + c];
        sum += v; ssq += v * v;
    }
    red[tid] = sum; red[256 + tid] = ssq;
    __syncthreads();
    if (tid < 64) {
        float s = red[tid] + red[tid+64] + red[tid+128] + red[tid+192];
        float q = red[256+tid] + red[256+tid+64] + red[256+tid+128] + red[256+tid+192];
        atomicAdd(&st[tid], s);
        atomicAdd(&st[64 + tid], q);
    }
}

// coef[c] = g*rsqrt(var+eps); coef[64+c] = beta - mean*coef[c]
__global__ void finalize_k(const float* __restrict__ st, const float* __restrict__ g,
                           const float* __restrict__ be, float* __restrict__ coef) {
    int c = threadIdx.x;
    float inv = 1.f / (float)RTOT;
    float mean = st[c] * inv;
    float var  = st[64 + c] * inv - mean * mean;
    float a = g[c] * rsqrtf(var + EPSF);
    coef[c] = a;
    coef[64 + c] = be[c] - mean * a;
}

// ---------------------------------------------------------------------------
// attention: one block (128 thr) per (head h, b*T+t). R=4 query rows/thread.
// K in LDS as channel-packed f16 (1 ds_read_b128 per key row);
// V in LDS as key-pair-interleaved f16 (2 ds_read_b128 per 2 keys).
// Scores & PV via v_dot2_f32_f16. Softmax without max (scores >= 0, bounded);
// uniform shift s-12 keeps p in f16 normal range (softmax-invariant).
// Masked query row -> q=0 -> uniform weights == reference -1e9 fill.
// ---------------------------------------------------------------------------
__global__ __launch_bounds__(128) void attn_kernel(
        const float* __restrict__ Yq, const float* __restrict__ Yk,
        const float* __restrict__ Yv, const float* __restrict__ mask,
        const float* __restrict__ cq, const float* __restrict__ ck,
        const float* __restrict__ cv, float* __restrict__ O) {
    __shared__ __align__(16) h2 KL[512][4];   // 8 KB
    __shared__ __align__(16) h2 VL[256][8];   // 8 KB
    int p = blockIdx.x;
    int h = p / 96;              // B*T = 96
    int bt = p - h * 96;
    int row0 = bt * 512;
    int co = h * 8;
    int tid = threadIdx.x;

    // stage K (BN+ReLU applied, f16 channel-packed)
#pragma unroll
    for (int i = 0; i < 4; i++) {
        int m = tid + 128 * i;
        const float4* yr = (const float4*)(Yk + (size_t)(row0 + m) * 64 + co);
        float4 y0 = yr[0], y1 = yr[1];
        float k0 = fmaxf(ck[co+0]*y0.x + ck[64+co+0], 0.f);
        float k1 = fmaxf(ck[co+1]*y0.y + ck[64+co+1], 0.f);
        float k2 = fmaxf(ck[co+2]*y0.z + ck[64+co+2], 0.f);
        float k3 = fmaxf(ck[co+3]*y0.w + ck[64+co+3], 0.f);
        float k4 = fmaxf(ck[co+4]*y1.x + ck[64+co+4], 0.f);
        float k5 = fmaxf(ck[co+5]*y1.y + ck[64+co+5], 0.f);
        float k6 = fmaxf(ck[co+6]*y1.z + ck[64+co+6], 0.f);
        float k7 = fmaxf(ck[co+7]*y1.w + ck[64+co+7], 0.f);
        uint4 kw;
        kw.x = bcu(cvt2h(k0, k1));
        kw.y = bcu(cvt2h(k2, k3));
        kw.z = bcu(cvt2h(k4, k5));
        kw.w = bcu(cvt2h(k6, k7));
        ((uint4*)KL)[m] = kw;
    }
    // stage V (BN+ReLU applied, key-pair interleaved: VL[j][c] = (V[2j][c],V[2j+1][c]))
#pragma unroll
    for (int i = 0; i < 2; i++) {
        int j = tid + 128 * i;
        const float4* ya = (const float4*)(Yv + (size_t)(row0 + 2*j) * 64 + co);
        const float4* yb = (const float4*)(Yv + (size_t)(row0 + 2*j + 1) * 64 + co);
        float4 a0 = ya[0], a1 = ya[1], b0 = yb[0], b1 = yb[1];
        float va[8], vb[8];
        va[0]=fmaxf(cv[co+0]*a0.x+cv[64+co+0],0.f); vb[0]=fmaxf(cv[co+0]*b0.x+cv[64+co+0],0.f);
        va[1]=fmaxf(cv[co+1]*a0.y+cv[64+co+1],0.f); vb[1]=fmaxf(cv[co+1]*b0.y+cv[64+co+1],0.f);
        va[2]=fmaxf(cv[co+2]*a0.z+cv[64+co+2],0.f); vb[2]=fmaxf(cv[co+2]*b0.z+cv[64+co+2],0.f);
        va[3]=fmaxf(cv[co+3]*a0.w+cv[64+co+3],0.f); vb[3]=fmaxf(cv[co+3]*b0.w+cv[64+co+3],0.f);
        va[4]=fmaxf(cv[co+4]*a1.x+cv[64+co+4],0.f); vb[4]=fmaxf(cv[co+4]*b1.x+cv[64+co+4],0.f);
        va[5]=fmaxf(cv[co+5]*a1.y+cv[64+co+5],0.f); vb[5]=fmaxf(cv[co+5]*b1.y+cv[64+co+5],0.f);
        va[6]=fmaxf(cv[co+6]*a1.z+cv[64+co+6],0.f); vb[6]=fmaxf(cv[co+6]*b1.z+cv[64+co+6],0.f);
        va[7]=fmaxf(cv[co+7]*a1.w+cv[64+co+7],0.f); vb[7]=fmaxf(cv[co+7]*b1.w+cv[64+co+7],0.f);
        uint4 w0, w1;
        w0.x = bcu(cvt2h(va[0], vb[0]));
        w0.y = bcu(cvt2h(va[1], vb[1]));
        w0.z = bcu(cvt2h(va[2], vb[2]));
        w0.w = bcu(cvt2h(va[3], vb[3]));
        w1.x = bcu(cvt2h(va[4], vb[4]));
        w1.y = bcu(cvt2h(va[5], vb[5]));
        w1.z = bcu(cvt2h(va[6], vb[6]));
        w1.w = bcu(cvt2h(va[7], vb[7]));
        ((uint4*)VL)[2*j]   = w0;
        ((uint4*)VL)[2*j+1] = w1;
    }

    // q prep: rows tid + 128*r, BN+ReLU, scale by log2e/sqrt(8), pack to f16
    const float SC = 0.35355339059327373f * 1.4426950408889634f;
    h2 qp[4][4];
#pragma unroll
    for (int r = 0; r < 4; r++) {
        int n = tid + 128 * r;
        const float4* yr = (const float4*)(Yq + (size_t)(row0 + n) * 64 + co);
        const float4* mr = (const float4*)(mask + (size_t)(row0 + n) * 64 + co);
        float4 y0 = yr[0], y1 = yr[1];
        float4 m0 = mr[0], m1 = mr[1];
        float msum = m0.x+m0.y+m0.z+m0.w + m1.x+m1.y+m1.z+m1.w;
        float zm = (msum == 0.f) ? 0.f : SC;
        float q0 = fmaxf(cq[co+0]*y0.x + cq[64+co+0], 0.f) * zm;
        float q1 = fmaxf(cq[co+1]*y0.y + cq[64+co+1], 0.f) * zm;
        float q2 = fmaxf(cq[co+2]*y0.z + cq[64+co+2], 0.f) * zm;
        float q3 = fmaxf(cq[co+3]*y0.w + cq[64+co+3], 0.f) * zm;
        float q4 = fmaxf(cq[co+4]*y1.x + cq[64+co+4], 0.f) * zm;
        float q5 = fmaxf(cq[co+5]*y1.y + cq[64+co+5], 0.f) * zm;
        float q6 = fmaxf(cq[co+6]*y1.z + cq[64+co+6], 0.f) * zm;
        float q7 = fmaxf(cq[co+7]*y1.w + cq[64+co+7], 0.f) * zm;
        qp[r][0] = cvt2h(q0, q1);
        qp[r][1] = cvt2h(q2, q3);
        qp[r][2] = cvt2h(q4, q5);
        qp[r][3] = cvt2h(q6, q7);
    }
    __syncthreads();

    float acc[4][8];
    float lsum[4] = {0.f, 0.f, 0.f, 0.f};
#pragma unroll
    for (int r = 0; r < 4; r++)
#pragma unroll
        for (int c = 0; c < 8; c++) acc[r][c] = 0.f;

    const uint4* KLu = (const uint4*)KL;
    const uint4* VLu = (const uint4*)VL;

#pragma unroll 2
    for (int j = 0; j < 256; j++) {
        uint4 ka = KLu[2*j], kb = KLu[2*j+1];
        uint4 va = VLu[2*j], vb = VLu[2*j+1];
        h2 k0[4] = {bch2(ka.x), bch2(ka.y), bch2(ka.z), bch2(ka.w)};
        h2 k1[4] = {bch2(kb.x), bch2(kb.y), bch2(kb.z), bch2(kb.w)};
        h2 vv[8] = {bch2(va.x), bch2(va.y), bch2(va.z), bch2(va.w),
                    bch2(vb.x), bch2(vb.y), bch2(vb.z), bch2(vb.w)};
#pragma unroll
        for (int r = 0; r < 4; r++) {
            // scores in log2 units, pre-shifted by -12 (softmax-invariant)
            float s0 = fdot2f(qp[r][3], k0[3],
                       fdot2f(qp[r][2], k0[2],
                       fdot2f(qp[r][1], k0[1],
                       fdot2f(qp[r][0], k0[0], -12.f))));
            float s1 = fdot2f(qp[r][3], k1[3],
                       fdot2f(qp[r][2], k1[2],
                       fdot2f(qp[r][1], k1[1],
                       fdot2f(qp[r][0], k1[0], -12.f))));
            float p0 = __builtin_amdgcn_exp2f(s0);
            float p1 = __builtin_amdgcn_exp2f(s1);
            lsum[r] += p0 + p1;
            h2 pp = cvt2h(p0, p1);
#pragma unroll
            for (int c = 0; c < 8; c++)
                acc[r][c] = fdot2f(pp, vv[c], acc[r][c]);
        }
    }

#pragma unroll
    for (int r = 0; r < 4; r++) {
        int n = tid + 128 * r;
        float rs = 1.f / lsum[r];
        float4* o = (float4*)&O[(size_t)(row0 + n) * 64 + co];
        o[0] = make_float4(acc[r][0]*rs, acc[r][1]*rs, acc[r][2]*rs, acc[r][3]*rs);
        o[1] = make_float4(acc[r][4]*rs, acc[r][5]*rs, acc[r][6]*rs, acc[r][7]*rs);
    }
}

// out = relu(a*y + b), float4-vectorized
__global__ __launch_bounds__(256) void norm_relu(const float* __restrict__ Y,
                                                 const float* __restrict__ coef,
                                                 float* __restrict__ out) {
    int i = blockIdx.x * 256 + threadIdx.x;
    float4 y = ((const float4*)Y)[i];
    int cb = (i & 15) * 4;
    float4 o;
    o.x = fmaxf(coef[cb+0]*y.x + coef[64+cb+0], 0.f);
    o.y = fmaxf(coef[cb+1]*y.y + coef[64+cb+1], 0.f);
    o.z = fmaxf(coef[cb+2]*y.z + coef[64+cb+2], 0.f);
    o.w = fmaxf(coef[cb+3]*y.w + coef[64+cb+3], 0.f);
    ((float4*)out)[i] = o;
}

extern "C" void kernel_launch(void* const* d_in, const int* in_sizes, int n_in,
                              void* d_out, int out_size, void* d_ws, size_t ws_size,
                              hipStream_t stream) {
    const float* Q    = (const float*)d_in[0];
    const float* Kin  = (const float*)d_in[1];
    const float* mask = (const float*)d_in[2];
    const float* Wq = (const float*)d_in[4];
    const float* bq = (const float*)d_in[5];
    const float* gq = (const float*)d_in[6];
    const float* betaq = (const float*)d_in[7];
    const float* Wk = (const float*)d_in[8];
    const float* bk = (const float*)d_in[9];
    const float* gk = (const float*)d_in[10];
    const float* betak = (const float*)d_in[11];
    const float* Wv = (const float*)d_in[12];
    const float* bv = (const float*)d_in[13];
    const float* gv = (const float*)d_in[14];
    const float* betav = (const float*)d_in[15];
    const float* Wo = (const float*)d_in[16];
    const float* bo = (const float*)d_in[17];
    const float* go = (const float*)d_in[18];
    const float* betao = (const float*)d_in[19];

    float* ws   = (float*)d_ws;
    const size_t TSZ = (size_t)RTOT * 64;
    float* Y0   = ws;              // Yq, later reused as Yo
    float* Y1   = ws + TSZ;        // Yk
    float* Y2   = ws + 2 * TSZ;    // Yv
    float* Obuf = ws + 3 * TSZ;    // merged attention output
    float* stats = ws + 4 * TSZ;   // 4 x 128 floats (sum, sumsq)
    float* coef  = stats + 512;    // 4 x 128 floats (a, b)

    (void)hipMemsetAsync(stats, 0, 512 * sizeof(float), stream);

    gemm_bias<<<RTOT/128, 128, 0, stream>>>(Q,   Wq, bq, Y0);
    gemm_bias<<<RTOT/128, 128, 0, stream>>>(Kin, Wk, bk, Y1);
    gemm_bias<<<RTOT/128, 128, 0, stream>>>(Kin, Wv, bv, Y2);

    stats_kernel<<<192, 256, 0, stream>>>(Y0, stats + 0);
    stats_kernel<<<192, 256, 0, stream>>>(Y1, stats + 128);
    stats_kernel<<<192, 256, 0, stream>>>(Y2, stats + 256);

    finalize_k<<<1, 64, 0, stream>>>(stats + 0,   gq, betaq, coef + 0);
    finalize_k<<<1, 64, 0, stream>>>(stats + 128, gk, betak, coef + 128);
    finalize_k<<<1, 64, 0, stream>>>(stats + 256, gv, betav, coef + 256);

    attn_kernel<<<768, 128, 0, stream>>>(Y0, Y1, Y2, mask,
                                         coef + 0, coef + 128, coef + 256, Obuf);

    gemm_bias<<<RTOT/128, 128, 0, stream>>>(Obuf, Wo, bo, Y0);
    stats_kernel<<<192, 256, 0, stream>>>(Y0, stats + 384);
    finalize_k<<<1, 64, 0, stream>>>(stats + 384, go, betao, coef + 384);

    norm_relu<<<(RTOT*64/4)/256, 256, 0, stream>>>(Y0, coef + 384, (float*)d_out);
}

// Round 4
// 259.837 us; speedup vs baseline: 1.2377x; 1.1814x over previous
//
#include <hip/hip_runtime.h>
#include <hip/hip_bf16.h>

#define BB 8
#define TT 12
#define NN 512
#define DD 64
#define RTOT (BB*TT*NN)   // 49152 rows
#define EPSF 1e-5f

typedef _Float16 h2 __attribute__((ext_vector_type(2)));
typedef _Float16 half8 __attribute__((ext_vector_type(8)));
typedef float f32x16 __attribute__((ext_vector_type(16)));

__device__ __forceinline__ h2 cvt2h(float a, float b) {
    return __builtin_bit_cast(h2, __builtin_amdgcn_cvt_pkrtz(a, b));
}
__device__ __forceinline__ unsigned int bcu(h2 v) { return __builtin_bit_cast(unsigned int, v); }

// exchange: x's hi-32-lane half <-> y's lo-32-lane half
__device__ __forceinline__ void swap32(unsigned int& x, unsigned int& y, int hi) {
#if __has_builtin(__builtin_amdgcn_permlane32_swap)
    auto r = __builtin_amdgcn_permlane32_swap(x, y, false, false);
    x = r[0]; y = r[1];
#else
    unsigned int xs = (unsigned int)__shfl_xor((int)x, 32, 64);
    unsigned int ys = (unsigned int)__shfl_xor((int)y, 32, 64);
    unsigned int nx = hi ? ys : x;
    unsigned int ny = hi ? y : xs;
    x = nx; y = ny;
#endif
}

// ---------------------------------------------------------------------------
// GEMM: Y[r][e] = sum_d X[r][d] * W[d][e] + bias[e]
// ---------------------------------------------------------------------------
__global__ __launch_bounds__(128) void gemm_bias(const float* __restrict__ X,
                                                 const float* __restrict__ W,
                                                 const float* __restrict__ bias,
                                                 float* __restrict__ Y) {
    __shared__ float Wl[4096];
    int tid = threadIdx.x;
    for (int i = tid; i < 1024; i += 128)
        ((float4*)Wl)[i] = ((const float4*)W)[i];
    __syncthreads();

    int row = blockIdx.x * 128 + tid;
    float x[64];
    const float4* xr = (const float4*)(X + (size_t)row * 64);
#pragma unroll
    for (int i = 0; i < 16; i++) {
        float4 t = xr[i];
        x[4*i] = t.x; x[4*i+1] = t.y; x[4*i+2] = t.z; x[4*i+3] = t.w;
    }
    float4* yo = (float4*)(Y + (size_t)row * 64);
#pragma unroll
    for (int ec = 0; ec < 4; ec++) {
        float acc[16];
#pragma unroll
        for (int j = 0; j < 16; j++) acc[j] = bias[ec*16 + j];
#pragma unroll 8
        for (int d = 0; d < 64; d++) {
            float xv = x[d];
            const float4* wr = (const float4*)&Wl[d*64 + ec*16];
            float4 w0 = wr[0], w1 = wr[1], w2 = wr[2], w3 = wr[3];
            acc[0]  += xv*w0.x; acc[1]  += xv*w0.y; acc[2]  += xv*w0.z; acc[3]  += xv*w0.w;
            acc[4]  += xv*w1.x; acc[5]  += xv*w1.y; acc[6]  += xv*w1.z; acc[7]  += xv*w1.w;
            acc[8]  += xv*w2.x; acc[9]  += xv*w2.y; acc[10] += xv*w2.z; acc[11] += xv*w2.w;
            acc[12] += xv*w3.x; acc[13] += xv*w3.y; acc[14] += xv*w3.z; acc[15] += xv*w3.w;
        }
        yo[ec*4+0] = make_float4(acc[0],  acc[1],  acc[2],  acc[3]);
        yo[ec*4+1] = make_float4(acc[4],  acc[5],  acc[6],  acc[7]);
        yo[ec*4+2] = make_float4(acc[8],  acc[9],  acc[10], acc[11]);
        yo[ec*4+3] = make_float4(acc[12], acc[13], acc[14], acc[15]);
    }
}

// ---------------------------------------------------------------------------
// per-channel sum / sumsq partials -> atomicAdd into st[0:64], st[64:128]
// ---------------------------------------------------------------------------
__global__ __launch_bounds__(256) void stats_kernel(const float* __restrict__ Y,
                                                    float* __restrict__ st) {
    __shared__ float red[512];
    int tid = threadIdx.x;
    int c = tid & 63;
    int g = tid >> 6;
    float sum = 0.f, ssq = 0.f;
    for (int r = blockIdx.x * 4 + g; r < RTOT; r += gridDim.x * 4) {
        float v = Y[(size_t)r * 64 + c];
        sum += v; ssq += v * v;
    }
    red[tid] = sum; red[256 + tid] = ssq;
    __syncthreads();
    if (tid < 64) {
        float s = red[tid] + red[tid+64] + red[tid+128] + red[tid+192];
        float q = red[256+tid] + red[256+tid+64] + red[256+tid+128] + red[256+tid+192];
        atomicAdd(&st[tid], s);
        atomicAdd(&st[64 + tid], q);
    }
}

// coef[c] = g*rsqrt(var+eps); coef[64+c] = beta - mean*coef[c]
__global__ void finalize_k(const float* __restrict__ st, const float* __restrict__ g,
                           const float* __restrict__ be, float* __restrict__ coef) {
    int c = threadIdx.x;
    float inv = 1.f / (float)RTOT;
    float mean = st[c] * inv;
    float var  = st[64 + c] * inv - mean * mean;
    float a = g[c] * rsqrtf(var + EPSF);
    coef[c] = a;
    coef[64 + c] = be[c] - mean * a;
}

// ---------------------------------------------------------------------------
// MFMA attention. One block (256 thr / 4 waves) per (head h, b*T+t) problem.
// Swapped QK^T: S^T tile = mfma_32x32x16_f16(Kfrag, Qfrag); k-dim 8 padded to
// 16 via exec-masked (hi-half zero) fragment loads. P = exp2(s-12) (softmax-
// invariant shift; scores >= 0). P->A-fragment via cvt_pk + permlane32_swap.
// PV: 2x mfma_32x32x16_f16 per 32-key tile against VS[m/8][c][8] interleaved
// LDS; V column 8 = ones makes the accumulator's c=8 lane the softmax
// denominator (no in-loop lsum).
// Masked query row -> q=0 -> uniform weights == reference -1e9 fill.
// ---------------------------------------------------------------------------
__global__ __launch_bounds__(256) void attn_mfma(
        const float* __restrict__ Yq, const float* __restrict__ Yk,
        const float* __restrict__ Yv, const float* __restrict__ mask,
        const float* __restrict__ cq, const float* __restrict__ ck,
        const float* __restrict__ cv, float* __restrict__ O) {
    __shared__ __align__(16) _Float16 KL[512 * 8];      // 8 KB, row-major [m][c]
    __shared__ __align__(16) _Float16 QL[512 * 8];      // 8 KB, row-major [n][c]
    __shared__ __align__(16) _Float16 VS[64 * 9 * 8];   // 9 KB, [m/8][c(0..8)][m%8]

    int p = blockIdx.x;
    int h = p / 96;              // B*T = 96
    int bt = p - h * 96;
    int row0 = bt * 512;
    int co = h * 8;
    int tid = threadIdx.x;

    const float SC = 0.35355339059327373f * 1.4426950408889634f; // 1/sqrt(8)*log2(e)

    // ---- stage K, Q (row-major f16) and V (chunk-interleaved f16) ----
#pragma unroll
    for (int rr = 0; rr < 2; rr++) {
        int m = tid + 256 * rr;
        size_t base = (size_t)(row0 + m) * 64 + co;
        // K
        {
            const float4* yr = (const float4*)(Yk + base);
            float4 y0 = yr[0], y1 = yr[1];
            half8 kv;
            kv[0] = (_Float16)fmaxf(ck[co+0]*y0.x + ck[64+co+0], 0.f);
            kv[1] = (_Float16)fmaxf(ck[co+1]*y0.y + ck[64+co+1], 0.f);
            kv[2] = (_Float16)fmaxf(ck[co+2]*y0.z + ck[64+co+2], 0.f);
            kv[3] = (_Float16)fmaxf(ck[co+3]*y0.w + ck[64+co+3], 0.f);
            kv[4] = (_Float16)fmaxf(ck[co+4]*y1.x + ck[64+co+4], 0.f);
            kv[5] = (_Float16)fmaxf(ck[co+5]*y1.y + ck[64+co+5], 0.f);
            kv[6] = (_Float16)fmaxf(ck[co+6]*y1.z + ck[64+co+6], 0.f);
            kv[7] = (_Float16)fmaxf(ck[co+7]*y1.w + ck[64+co+7], 0.f);
            *(half8*)&KL[m * 8] = kv;
        }
        // Q (mask + scale folded in)
        {
            const float4* yr = (const float4*)(Yq + base);
            const float4* mr = (const float4*)(mask + base);
            float4 y0 = yr[0], y1 = yr[1];
            float4 m0 = mr[0], m1 = mr[1];
            float msum = m0.x+m0.y+m0.z+m0.w + m1.x+m1.y+m1.z+m1.w;
            float zm = (msum == 0.f) ? 0.f : SC;
            half8 qv;
            qv[0] = (_Float16)(fmaxf(cq[co+0]*y0.x + cq[64+co+0], 0.f) * zm);
            qv[1] = (_Float16)(fmaxf(cq[co+1]*y0.y + cq[64+co+1], 0.f) * zm);
            qv[2] = (_Float16)(fmaxf(cq[co+2]*y0.z + cq[64+co+2], 0.f) * zm);
            qv[3] = (_Float16)(fmaxf(cq[co+3]*y0.w + cq[64+co+3], 0.f) * zm);
            qv[4] = (_Float16)(fmaxf(cq[co+4]*y1.x + cq[64+co+4], 0.f) * zm);
            qv[5] = (_Float16)(fmaxf(cq[co+5]*y1.y + cq[64+co+5], 0.f) * zm);
            qv[6] = (_Float16)(fmaxf(cq[co+6]*y1.z + cq[64+co+6], 0.f) * zm);
            qv[7] = (_Float16)(fmaxf(cq[co+7]*y1.w + cq[64+co+7], 0.f) * zm);
            *(half8*)&QL[m * 8] = qv;
        }
        // V scatter into [chunk][c][i]
        {
            const float4* yr = (const float4*)(Yv + base);
            float4 y0 = yr[0], y1 = yr[1];
            _Float16 vv[8];
            vv[0] = (_Float16)fmaxf(cv[co+0]*y0.x + cv[64+co+0], 0.f);
            vv[1] = (_Float16)fmaxf(cv[co+1]*y0.y + cv[64+co+1], 0.f);
            vv[2] = (_Float16)fmaxf(cv[co+2]*y0.z + cv[64+co+2], 0.f);
            vv[3] = (_Float16)fmaxf(cv[co+3]*y0.w + cv[64+co+3], 0.f);
            vv[4] = (_Float16)fmaxf(cv[co+4]*y1.x + cv[64+co+4], 0.f);
            vv[5] = (_Float16)fmaxf(cv[co+5]*y1.y + cv[64+co+5], 0.f);
            vv[6] = (_Float16)fmaxf(cv[co+6]*y1.z + cv[64+co+6], 0.f);
            vv[7] = (_Float16)fmaxf(cv[co+7]*y1.w + cv[64+co+7], 0.f);
            int ch = m >> 3, ii = m & 7;
#pragma unroll
            for (int c = 0; c < 8; c++)
                VS[ch * 72 + c * 8 + ii] = vv[c];
        }
    }
    // ones column (c = 8) -> denominator accumulates in PV
    if (tid < 64) {
        half8 one8;
#pragma unroll
        for (int i = 0; i < 8; i++) one8[i] = (_Float16)1.0f;
        *(half8*)&VS[tid * 72 + 64] = one8;
    }
    __syncthreads();

    int wv = tid >> 6;
    int lane = tid & 63;
    int ln = lane & 31;
    int hi = lane >> 5;

    f32x16 zacc;
#pragma unroll
    for (int r = 0; r < 16; r++) zacc[r] = 0.f;
    half8 hzero;
#pragma unroll
    for (int i = 0; i < 8; i++) hzero[i] = (_Float16)0.f;

    // 16 query-strips of 32 rows; wave wv handles strips wv, wv+4, wv+8, wv+12
    for (int si = wv; si < 16; si += 4) {
        int n0 = si * 32;
        half8 qf = hzero;
        if (!hi) qf = *(const half8*)&QL[(n0 + ln) * 8];
        f32x16 acc = zacc;

#pragma unroll 4
        for (int t = 0; t < 16; t++) {
            half8 kf = hzero;
            if (!hi) kf = *(const half8*)&KL[(t * 32 + ln) * 8];
            f32x16 sv = __builtin_amdgcn_mfma_f32_32x32x16_f16(kf, qf, zacc, 0, 0, 0);
            float pe[16];
#pragma unroll
            for (int r = 0; r < 16; r++)
                pe[r] = __builtin_amdgcn_exp2f(sv[r] - 12.f);
#pragma unroll
            for (int ks = 0; ks < 2; ks++) {
                unsigned int x1 = bcu(cvt2h(pe[8*ks+0], pe[8*ks+1]));
                unsigned int x2 = bcu(cvt2h(pe[8*ks+2], pe[8*ks+3]));
                unsigned int y1 = bcu(cvt2h(pe[8*ks+4], pe[8*ks+5]));
                unsigned int y2 = bcu(cvt2h(pe[8*ks+6], pe[8*ks+7]));
                swap32(x1, y1, hi);
                swap32(x2, y2, hi);
                uint4 pw = make_uint4(x1, x2, y1, y2);
                half8 pa = __builtin_bit_cast(half8, pw);
                int chunk = t * 4 + ks * 2 + hi;
                half8 vf = hzero;
                if (ln <= 8) vf = *(const half8*)&VS[chunk * 72 + ln * 8];
                acc = __builtin_amdgcn_mfma_f32_32x32x16_f16(pa, vf, acc, 0, 0, 0);
            }
        }

        // epilogue: c=8 lane of acc holds the softmax denominator
#pragma unroll
        for (int r = 0; r < 16; r++) {
            float av = acc[r];
            float den = __shfl(av, 8 + 32 * hi, 64);
            float ov = av * __builtin_amdgcn_rcpf(den);
            if (ln < 8) {
                int nrow = n0 + (r & 3) + 8 * (r >> 2) + 4 * hi;
                O[(size_t)(row0 + nrow) * 64 + co + ln] = ov;
            }
        }
    }
}

// out = relu(a*y + b), float4-vectorized
__global__ __launch_bounds__(256) void norm_relu(const float* __restrict__ Y,
                                                 const float* __restrict__ coef,
                                                 float* __restrict__ out) {
    int i = blockIdx.x * 256 + threadIdx.x;
    float4 y = ((const float4*)Y)[i];
    int cb = (i & 15) * 4;
    float4 o;
    o.x = fmaxf(coef[cb+0]*y.x + coef[64+cb+0], 0.f);
    o.y = fmaxf(coef[cb+1]*y.y + coef[64+cb+1], 0.f);
    o.z = fmaxf(coef[cb+2]*y.z + coef[64+cb+2], 0.f);
    o.w = fmaxf(coef[cb+3]*y.w + coef[64+cb+3], 0.f);
    ((float4*)out)[i] = o;
}

extern "C" void kernel_launch(void* const* d_in, const int* in_sizes, int n_in,
                              void* d_out, int out_size, void* d_ws, size_t ws_size,
                              hipStream_t stream) {
    const float* Q    = (const float*)d_in[0];
    const float* Kin  = (const float*)d_in[1];
    const float* mask = (const float*)d_in[2];
    const float* Wq = (const float*)d_in[4];
    const float* bq = (const float*)d_in[5];
    const float* gq = (const float*)d_in[6];
    const float* betaq = (const float*)d_in[7];
    const float* Wk = (const float*)d_in[8];
    const float* bk = (const float*)d_in[9];
    const float* gk = (const float*)d_in[10];
    const float* betak = (const float*)d_in[11];
    const float* Wv = (const float*)d_in[12];
    const float* bv = (const float*)d_in[13];
    const float* gv = (const float*)d_in[14];
    const float* betav = (const float*)d_in[15];
    const float* Wo = (const float*)d_in[16];
    const float* bo = (const float*)d_in[17];
    const float* go = (const float*)d_in[18];
    const float* betao = (const float*)d_in[19];

    float* ws   = (float*)d_ws;
    const size_t TSZ = (size_t)RTOT * 64;
    float* Y0   = ws;              // Yq, later reused as Yo
    float* Y1   = ws + TSZ;        // Yk
    float* Y2   = ws + 2 * TSZ;    // Yv
    float* Obuf = ws + 3 * TSZ;    // merged attention output
    float* stats = ws + 4 * TSZ;   // 4 x 128 floats (sum, sumsq)
    float* coef  = stats + 512;    // 4 x 128 floats (a, b)

    (void)hipMemsetAsync(stats, 0, 512 * sizeof(float), stream);

    gemm_bias<<<RTOT/128, 128, 0, stream>>>(Q,   Wq, bq, Y0);
    gemm_bias<<<RTOT/128, 128, 0, stream>>>(Kin, Wk, bk, Y1);
    gemm_bias<<<RTOT/128, 128, 0, stream>>>(Kin, Wv, bv, Y2);

    stats_kernel<<<192, 256, 0, stream>>>(Y0, stats + 0);
    stats_kernel<<<192, 256, 0, stream>>>(Y1, stats + 128);
    stats_kernel<<<192, 256, 0, stream>>>(Y2, stats + 256);

    finalize_k<<<1, 64, 0, stream>>>(stats + 0,   gq, betaq, coef + 0);
    finalize_k<<<1, 64, 0, stream>>>(stats + 128, gk, betak, coef + 128);
    finalize_k<<<1, 64, 0, stream>>>(stats + 256, gv, betav, coef + 256);

    attn_mfma<<<768, 256, 0, stream>>>(Y0, Y1, Y2, mask,
                                       coef + 0, coef + 128, coef + 256, Obuf);

    gemm_bias<<<RTOT/128, 128, 0, stream>>>(Obuf, Wo, bo, Y0);
    stats_kernel<<<192, 256, 0, stream>>>(Y0, stats + 384);
    finalize_k<<<1, 64, 0, stream>>>(stats + 384, go, betao, coef + 384);

    norm_relu<<<(RTOT*64/4)/256, 256, 0, stream>>>(Y0, coef + 384, (float*)d_out);
}

// Round 5
// 154.758 us; speedup vs baseline: 2.0781x; 1.6790x over previous
//
#include <hip/hip_runtime.h>
#include <hip/hip_bf16.h>

#define RTOT 49152
#define EPSF 1e-5f

typedef _Float16 h2 __attribute__((ext_vector_type(2)));
typedef _Float16 half8 __attribute__((ext_vector_type(8)));
typedef float f32x16 __attribute__((ext_vector_type(16)));

__device__ __forceinline__ h2 cvt2h(float a, float b) {
    return __builtin_bit_cast(h2, __builtin_amdgcn_cvt_pkrtz(a, b));
}
__device__ __forceinline__ unsigned int bcu(h2 v) { return __builtin_bit_cast(unsigned int, v); }

// exchange: x's hi-32-lane half <-> y's lo-32-lane half
__device__ __forceinline__ void swap32(unsigned int& x, unsigned int& y, int hi) {
#if __has_builtin(__builtin_amdgcn_permlane32_swap)
    auto r = __builtin_amdgcn_permlane32_swap(x, y, false, false);
    x = r[0]; y = r[1];
#else
    unsigned int xs = (unsigned int)__shfl_xor((int)x, 32, 64);
    unsigned int ys = (unsigned int)__shfl_xor((int)y, 32, 64);
    unsigned int nx = hi ? ys : x;
    unsigned int ny = hi ? y : xs;
    x = nx; y = ny;
#endif
}

// ---------------------------------------------------------------------------
// MFMA GEMM + fused BN-stats. Block = 256 thr / 4 waves, 256 rows.
// Wave w: rows w*64..w*64+63 (2 row-tiles x 2 col-tiles x 4 k-chunks).
// W staged transposed f16 in LDS, XOR-swizzled (T2). Y stored f16; per-channel
// sum/sumsq computed from fp32 accumulators -> global atomicAdd.
// Fragment layout (verified on-device in R4): A/B lane&31 = M/N index,
// lane>>5 = k-half, 8 contiguous k; D row=(r&3)+8(r>>2)+4hi, col=lane&31.
// ---------------------------------------------------------------------------
template<int F16IN, int NOUT>
__global__ __launch_bounds__(256) void gemm_mfma(
        const void* __restrict__ Xraw,
        const float* __restrict__ Wa, const float* __restrict__ ba,
        _Float16* __restrict__ Ya, float* __restrict__ sta,
        const float* __restrict__ Wb, const float* __restrict__ bb,
        _Float16* __restrict__ Yb, float* __restrict__ stb) {
    __shared__ char WT[NOUT][8192];   // W^T as f16, swizzled
    int tid = threadIdx.x;
#pragma unroll
    for (int o = 0; o < NOUT; o++) {
        const float* W = o ? Wb : Wa;
        for (int i = tid; i < 4096; i += 256) {
            int d = i >> 6, e = i & 63;          // coalesced read of W[d][e]
            int off = ((e * 64 + d) * 2) ^ ((e & 7) << 4);
            *(_Float16*)(&WT[o][off]) = (_Float16)W[i];
        }
    }
    int wv = tid >> 6, lane = tid & 63, ln = lane & 31, hi = lane >> 5;
    int rbase = blockIdx.x * 256 + wv * 64;

    // A fragments: af[rt][kc], row = rbase+rt*32+ln, k = kc*16+8*hi .. +7
    half8 af[2][4];
    if constexpr (F16IN) {
        const _Float16* X = (const _Float16*)Xraw;
#pragma unroll
        for (int rt = 0; rt < 2; rt++)
#pragma unroll
            for (int kc = 0; kc < 4; kc++)
                af[rt][kc] = *(const half8*)(X + (size_t)(rbase + rt*32 + ln) * 64 + kc*16 + 8*hi);
    } else {
        const float* X = (const float*)Xraw;
#pragma unroll
        for (int rt = 0; rt < 2; rt++)
#pragma unroll
            for (int kc = 0; kc < 4; kc++) {
                const float4* p = (const float4*)(X + (size_t)(rbase + rt*32 + ln) * 64 + kc*16 + 8*hi);
                float4 x = p[0], y = p[1];
                uint4 u = make_uint4(bcu(cvt2h(x.x, x.y)), bcu(cvt2h(x.z, x.w)),
                                     bcu(cvt2h(y.x, y.y)), bcu(cvt2h(y.z, y.w)));
                af[rt][kc] = __builtin_bit_cast(half8, u);
            }
    }
    __syncthreads();

#pragma unroll
    for (int o = 0; o < NOUT; o++) {
        const float* bias = o ? bb : ba;
        float* st = o ? stb : sta;
        _Float16* Y = o ? Yb : Ya;

        half8 bf[2][4];
#pragma unroll
        for (int ct = 0; ct < 2; ct++)
#pragma unroll
            for (int kc = 0; kc < 4; kc++) {
                int e = ct * 32 + ln;
                int off = ((e * 64 + kc * 16 + 8 * hi) * 2) ^ ((e & 7) << 4);
                bf[ct][kc] = *(const half8*)(&WT[o][off]);
            }

        f32x16 acc[2][2];
#pragma unroll
        for (int rt = 0; rt < 2; rt++)
#pragma unroll
            for (int ct = 0; ct < 2; ct++) {
#pragma unroll
                for (int r = 0; r < 16; r++) acc[rt][ct][r] = 0.f;
#pragma unroll
                for (int kc = 0; kc < 4; kc++)
                    acc[rt][ct] = __builtin_amdgcn_mfma_f32_32x32x16_f16(
                        af[rt][kc], bf[ct][kc], acc[rt][ct], 0, 0, 0);
            }

#pragma unroll
        for (int ct = 0; ct < 2; ct++) {
            float bv = bias[ct * 32 + ln];
            float s = 0.f, q = 0.f;
#pragma unroll
            for (int rt = 0; rt < 2; rt++)
#pragma unroll
                for (int r = 0; r < 16; r++) {
                    float v = acc[rt][ct][r] + bv;
                    s += v; q += v * v;
                    int row = rbase + rt*32 + (r & 3) + 8*(r >> 2) + 4*hi;
                    Y[(size_t)row * 64 + ct*32 + ln] = (_Float16)v;
                }
            s += __shfl_xor(s, 32, 64);
            q += __shfl_xor(q, 32, 64);
            if (lane < 32) {
                atomicAdd(&st[ct*32 + ln], s);
                atomicAdd(&st[64 + ct*32 + ln], q);
            }
        }
    }
}

// coef[c] = g*rsqrt(var+eps); coef[64+c] = beta - mean*coef[c]; 3 sets at once
__global__ void finalize3(const float* __restrict__ st,
                          const float* g0, const float* b0,
                          const float* g1, const float* b1,
                          const float* g2, const float* b2,
                          float* __restrict__ coef) {
    int t = threadIdx.x;
    int s = t >> 6, c = t & 63;
    const float* g  = s == 0 ? g0 : (s == 1 ? g1 : g2);
    const float* be = s == 0 ? b0 : (s == 1 ? b1 : b2);
    const float* stp = st + s * 128;
    float inv = 1.f / (float)RTOT;
    float mean = stp[c] * inv;
    float var  = stp[64 + c] * inv - mean * mean;
    float a = g[c] * rsqrtf(var + EPSF);
    coef[s*128 + c] = a;
    coef[s*128 + 64 + c] = be[c] - mean * a;
}

__global__ void finalize_k(const float* __restrict__ st, const float* __restrict__ g,
                           const float* __restrict__ be, float* __restrict__ coef) {
    int c = threadIdx.x;
    float inv = 1.f / (float)RTOT;
    float mean = st[c] * inv;
    float var  = st[64 + c] * inv - mean * mean;
    float a = g[c] * rsqrtf(var + EPSF);
    coef[c] = a;
    coef[64 + c] = be[c] - mean * a;
}

// ---------------------------------------------------------------------------
// MFMA attention (as R4), now consuming f16 Y and writing f16 O.
// ---------------------------------------------------------------------------
__global__ __launch_bounds__(256) void attn_mfma(
        const _Float16* __restrict__ Yq, const _Float16* __restrict__ Yk,
        const _Float16* __restrict__ Yv, const float* __restrict__ mask,
        const float* __restrict__ cq, const float* __restrict__ ck,
        const float* __restrict__ cv, _Float16* __restrict__ O) {
    __shared__ __align__(16) _Float16 KL[512 * 8];      // 8 KB, row-major [m][c]
    __shared__ __align__(16) _Float16 QL[512 * 8];      // 8 KB, row-major [n][c]
    __shared__ __align__(16) _Float16 VS[64 * 9 * 8];   // 9 KB, [m/8][c(0..8)][m%8]

    int p = blockIdx.x;
    int h = p / 96;              // B*T = 96
    int bt = p - h * 96;
    int row0 = bt * 512;
    int co = h * 8;
    int tid = threadIdx.x;

    const float SC = 0.35355339059327373f * 1.4426950408889634f; // 1/sqrt(8)*log2(e)

#pragma unroll
    for (int rr = 0; rr < 2; rr++) {
        int m = tid + 256 * rr;
        size_t base = (size_t)(row0 + m) * 64 + co;
        // K
        {
            half8 y = *(const half8*)(Yk + base);
            half8 kv;
#pragma unroll
            for (int c = 0; c < 8; c++)
                kv[c] = (_Float16)fmaxf(ck[co+c] * (float)y[c] + ck[64+co+c], 0.f);
            *(half8*)&KL[m * 8] = kv;
        }
        // Q (mask + scale folded in)
        {
            half8 y = *(const half8*)(Yq + base);
            const float4* mr = (const float4*)(mask + base);
            float4 m0 = mr[0], m1 = mr[1];
            float msum = m0.x+m0.y+m0.z+m0.w + m1.x+m1.y+m1.z+m1.w;
            float zm = (msum == 0.f) ? 0.f : SC;
            half8 qv;
#pragma unroll
            for (int c = 0; c < 8; c++)
                qv[c] = (_Float16)(fmaxf(cq[co+c] * (float)y[c] + cq[64+co+c], 0.f) * zm);
            *(half8*)&QL[m * 8] = qv;
        }
        // V scatter into [chunk][c][i]
        {
            half8 y = *(const half8*)(Yv + base);
            int ch = m >> 3, ii = m & 7;
#pragma unroll
            for (int c = 0; c < 8; c++)
                VS[ch * 72 + c * 8 + ii] =
                    (_Float16)fmaxf(cv[co+c] * (float)y[c] + cv[64+co+c], 0.f);
        }
    }
    // ones column (c = 8) -> denominator accumulates in PV
    if (tid < 64) {
        half8 one8;
#pragma unroll
        for (int i = 0; i < 8; i++) one8[i] = (_Float16)1.0f;
        *(half8*)&VS[tid * 72 + 64] = one8;
    }
    __syncthreads();

    int wv = tid >> 6;
    int lane = tid & 63;
    int ln = lane & 31;
    int hi = lane >> 5;

    f32x16 zacc;
#pragma unroll
    for (int r = 0; r < 16; r++) zacc[r] = 0.f;
    half8 hzero;
#pragma unroll
    for (int i = 0; i < 8; i++) hzero[i] = (_Float16)0.f;

    for (int si = wv; si < 16; si += 4) {
        int n0 = si * 32;
        half8 qf = hzero;
        if (!hi) qf = *(const half8*)&QL[(n0 + ln) * 8];
        f32x16 acc = zacc;

#pragma unroll 4
        for (int t = 0; t < 16; t++) {
            half8 kf = hzero;
            if (!hi) kf = *(const half8*)&KL[(t * 32 + ln) * 8];
            f32x16 sv = __builtin_amdgcn_mfma_f32_32x32x16_f16(kf, qf, zacc, 0, 0, 0);
            float pe[16];
#pragma unroll
            for (int r = 0; r < 16; r++)
                pe[r] = __builtin_amdgcn_exp2f(sv[r] - 12.f);
#pragma unroll
            for (int ks = 0; ks < 2; ks++) {
                unsigned int x1 = bcu(cvt2h(pe[8*ks+0], pe[8*ks+1]));
                unsigned int x2 = bcu(cvt2h(pe[8*ks+2], pe[8*ks+3]));
                unsigned int y1 = bcu(cvt2h(pe[8*ks+4], pe[8*ks+5]));
                unsigned int y2 = bcu(cvt2h(pe[8*ks+6], pe[8*ks+7]));
                swap32(x1, y1, hi);
                swap32(x2, y2, hi);
                uint4 pw = make_uint4(x1, x2, y1, y2);
                half8 pa = __builtin_bit_cast(half8, pw);
                int chunk = t * 4 + ks * 2 + hi;
                half8 vf = hzero;
                if (ln <= 8) vf = *(const half8*)&VS[chunk * 72 + ln * 8];
                acc = __builtin_amdgcn_mfma_f32_32x32x16_f16(pa, vf, acc, 0, 0, 0);
            }
        }

        // epilogue: c=8 lane of acc holds the softmax denominator
#pragma unroll
        for (int r = 0; r < 16; r++) {
            float av = acc[r];
            float den = __shfl(av, 8 + 32 * hi, 64);
            float ov = av * __builtin_amdgcn_rcpf(den);
            if (ln < 8) {
                int nrow = n0 + (r & 3) + 8 * (r >> 2) + 4 * hi;
                O[(size_t)(row0 + nrow) * 64 + co + ln] = (_Float16)ov;
            }
        }
    }
}

// out = relu(a*y + b) from f16 Y, 8 elems/thread
__global__ __launch_bounds__(256) void norm_relu16(const _Float16* __restrict__ Y,
                                                   const float* __restrict__ coef,
                                                   float* __restrict__ out) {
    int i = blockIdx.x * 256 + threadIdx.x;
    half8 y = ((const half8*)Y)[i];
    int cb = (i & 7) * 8;
    float4 o0, o1;
    o0.x = fmaxf(coef[cb+0]*(float)y[0] + coef[64+cb+0], 0.f);
    o0.y = fmaxf(coef[cb+1]*(float)y[1] + coef[64+cb+1], 0.f);
    o0.z = fmaxf(coef[cb+2]*(float)y[2] + coef[64+cb+2], 0.f);
    o0.w = fmaxf(coef[cb+3]*(float)y[3] + coef[64+cb+3], 0.f);
    o1.x = fmaxf(coef[cb+4]*(float)y[4] + coef[64+cb+4], 0.f);
    o1.y = fmaxf(coef[cb+5]*(float)y[5] + coef[64+cb+5], 0.f);
    o1.z = fmaxf(coef[cb+6]*(float)y[6] + coef[64+cb+6], 0.f);
    o1.w = fmaxf(coef[cb+7]*(float)y[7] + coef[64+cb+7], 0.f);
    ((float4*)out)[2*i]   = o0;
    ((float4*)out)[2*i+1] = o1;
}

extern "C" void kernel_launch(void* const* d_in, const int* in_sizes, int n_in,
                              void* d_out, int out_size, void* d_ws, size_t ws_size,
                              hipStream_t stream) {
    const float* Q    = (const float*)d_in[0];
    const float* Kin  = (const float*)d_in[1];
    const float* mask = (const float*)d_in[2];
    const float* Wq = (const float*)d_in[4];
    const float* bq = (const float*)d_in[5];
    const float* gq = (const float*)d_in[6];
    const float* betaq = (const float*)d_in[7];
    const float* Wk = (const float*)d_in[8];
    const float* bk = (const float*)d_in[9];
    const float* gk = (const float*)d_in[10];
    const float* betak = (const float*)d_in[11];
    const float* Wv = (const float*)d_in[12];
    const float* bv = (const float*)d_in[13];
    const float* gv = (const float*)d_in[14];
    const float* betav = (const float*)d_in[15];
    const float* Wo = (const float*)d_in[16];
    const float* bo = (const float*)d_in[17];
    const float* go = (const float*)d_in[18];
    const float* betao = (const float*)d_in[19];

    const size_t TSZ = (size_t)RTOT * 64;
    _Float16* Yq = (_Float16*)d_ws;
    _Float16* Yk = Yq + TSZ;
    _Float16* Yv = Yk + TSZ;
    _Float16* Ob = Yv + TSZ;
    _Float16* Yo = Ob + TSZ;
    float* stats = (float*)(Yo + TSZ);   // 512 floats (4 x {sum64, ssq64})
    float* coef  = stats + 512;          // 512 floats (4 x {a64, b64})

    (void)hipMemsetAsync(stats, 0, 512 * sizeof(float), stream);

    gemm_mfma<0,1><<<RTOT/256, 256, 0, stream>>>(Q, Wq, bq, Yq, stats + 0,
                                                 nullptr, nullptr, nullptr, nullptr);
    gemm_mfma<0,2><<<RTOT/256, 256, 0, stream>>>(Kin, Wk, bk, Yk, stats + 128,
                                                 Wv, bv, Yv, stats + 256);

    finalize3<<<1, 192, 0, stream>>>(stats, gq, betaq, gk, betak, gv, betav, coef);

    attn_mfma<<<768, 256, 0, stream>>>(Yq, Yk, Yv, mask,
                                       coef + 0, coef + 128, coef + 256, Ob);

    gemm_mfma<1,1><<<RTOT/256, 256, 0, stream>>>(Ob, Wo, bo, Yo, stats + 384,
                                                 nullptr, nullptr, nullptr, nullptr);
    finalize_k<<<1, 64, 0, stream>>>(stats + 384, go, betao, coef + 384);

    norm_relu16<<<(RTOT*64/8)/256, 256, 0, stream>>>(Yo, coef + 384, (float*)d_out);
}

// Round 6
// 115.068 us; speedup vs baseline: 2.7949x; 1.3449x over previous
//
#include <hip/hip_runtime.h>
#include <hip/hip_bf16.h>

#define RTOT 49152
#define EPSF 1e-5f

typedef _Float16 h2 __attribute__((ext_vector_type(2)));
typedef _Float16 half8 __attribute__((ext_vector_type(8)));
typedef float f32x16 __attribute__((ext_vector_type(16)));

__device__ __forceinline__ h2 cvt2h(float a, float b) {
    return __builtin_bit_cast(h2, __builtin_amdgcn_cvt_pkrtz(a, b));
}
__device__ __forceinline__ unsigned int bcu(h2 v) { return __builtin_bit_cast(unsigned int, v); }

// exchange: x's hi-32-lane half <-> y's lo-32-lane half
__device__ __forceinline__ void swap32(unsigned int& x, unsigned int& y, int hi) {
#if __has_builtin(__builtin_amdgcn_permlane32_swap)
    auto r = __builtin_amdgcn_permlane32_swap(x, y, false, false);
    x = r[0]; y = r[1];
#else
    unsigned int xs = (unsigned int)__shfl_xor((int)x, 32, 64);
    unsigned int ys = (unsigned int)__shfl_xor((int)y, 32, 64);
    unsigned int nx = hi ? ys : x;
    unsigned int ny = hi ? y : xs;
    x = nx; y = ny;
#endif
}

// ---------------------------------------------------------------------------
// Fused Q / K / V projection. grid (192, 2): y==0 -> X=Q, W=Wq -> Yq;
// y==1 -> X=Kin, W={Wk,Wv} -> Yk,Yv. BN stats fused (fp32 acc -> atomicAdd).
// Fragment layout (verified R4/R5): A/B lane&31 = M/N idx, lane>>5 = k-half;
// D row=(r&3)+8(r>>2)+4hi, col=lane&31.
// ---------------------------------------------------------------------------
__global__ __launch_bounds__(256) void gemm_qkv(
        const float* __restrict__ Qin, const float* __restrict__ Kin,
        const float* __restrict__ Wq, const float* __restrict__ bq,
        const float* __restrict__ Wk, const float* __restrict__ bk,
        const float* __restrict__ Wv, const float* __restrict__ bv,
        _Float16* __restrict__ Yq, _Float16* __restrict__ Yk,
        _Float16* __restrict__ Yv, float* __restrict__ stats) {
    __shared__ char WT[2][8192];   // W^T as f16, XOR-swizzled
    int tid = threadIdx.x;
    int which = blockIdx.y;
    const float* X = which ? Kin : Qin;

    {
        const float* W0 = which ? Wk : Wq;
        for (int i = tid; i < 4096; i += 256) {
            int d = i >> 6, e = i & 63;
            int off = ((e * 64 + d) * 2) ^ ((e & 7) << 4);
            *(_Float16*)(&WT[0][off]) = (_Float16)W0[i];
        }
        if (which) {
            for (int i = tid; i < 4096; i += 256) {
                int d = i >> 6, e = i & 63;
                int off = ((e * 64 + d) * 2) ^ ((e & 7) << 4);
                *(_Float16*)(&WT[1][off]) = (_Float16)Wv[i];
            }
        }
    }
    int wvi = tid >> 6, lane = tid & 63, ln = lane & 31, hi = lane >> 5;
    int rbase = blockIdx.x * 256 + wvi * 64;

    half8 af[2][4];
#pragma unroll
    for (int rt = 0; rt < 2; rt++)
#pragma unroll
        for (int kc = 0; kc < 4; kc++) {
            const float4* p = (const float4*)(X + (size_t)(rbase + rt*32 + ln) * 64 + kc*16 + 8*hi);
            float4 x = p[0], y = p[1];
            uint4 u = make_uint4(bcu(cvt2h(x.x, x.y)), bcu(cvt2h(x.z, x.w)),
                                 bcu(cvt2h(y.x, y.y)), bcu(cvt2h(y.z, y.w)));
            af[rt][kc] = __builtin_bit_cast(half8, u);
        }
    __syncthreads();

    int no = which ? 2 : 1;
    for (int o = 0; o < no; o++) {
        const float* bias = which ? (o ? bv : bk) : bq;
        float* st = stats + (which ? (o ? 256 : 128) : 0);
        _Float16* Y = which ? (o ? Yv : Yk) : Yq;

        half8 bf[2][4];
#pragma unroll
        for (int ct = 0; ct < 2; ct++)
#pragma unroll
            for (int kc = 0; kc < 4; kc++) {
                int e = ct * 32 + ln;
                int off = ((e * 64 + kc * 16 + 8 * hi) * 2) ^ ((e & 7) << 4);
                bf[ct][kc] = *(const half8*)(&WT[o][off]);
            }

        f32x16 acc[2][2];
#pragma unroll
        for (int rt = 0; rt < 2; rt++)
#pragma unroll
            for (int ct = 0; ct < 2; ct++) {
#pragma unroll
                for (int r = 0; r < 16; r++) acc[rt][ct][r] = 0.f;
#pragma unroll
                for (int kc = 0; kc < 4; kc++)
                    acc[rt][ct] = __builtin_amdgcn_mfma_f32_32x32x16_f16(
                        af[rt][kc], bf[ct][kc], acc[rt][ct], 0, 0, 0);
            }

#pragma unroll
        for (int ct = 0; ct < 2; ct++) {
            float bv_ = bias[ct * 32 + ln];
            float s = 0.f, q = 0.f;
#pragma unroll
            for (int rt = 0; rt < 2; rt++)
#pragma unroll
                for (int r = 0; r < 16; r++) {
                    float v = acc[rt][ct][r] + bv_;
                    s += v; q += v * v;
                    int row = rbase + rt*32 + (r & 3) + 8*(r >> 2) + 4*hi;
                    Y[(size_t)row * 64 + ct*32 + ln] = (_Float16)v;
                }
            s += __shfl_xor(s, 32, 64);
            q += __shfl_xor(q, 32, 64);
            if (lane < 32) {
                atomicAdd(&st[ct*32 + ln], s);
                atomicAdd(&st[64 + ct*32 + ln], q);
            }
        }
    }
}

// ---------------------------------------------------------------------------
// O-projection GEMM (f16 input) + fused stats. Same structure, single output.
// ---------------------------------------------------------------------------
__global__ __launch_bounds__(256) void gemm_o(
        const _Float16* __restrict__ X,
        const float* __restrict__ Wa, const float* __restrict__ ba,
        _Float16* __restrict__ Ya, float* __restrict__ sta) {
    __shared__ char WT[8192];
    int tid = threadIdx.x;
    for (int i = tid; i < 4096; i += 256) {
        int d = i >> 6, e = i & 63;
        int off = ((e * 64 + d) * 2) ^ ((e & 7) << 4);
        *(_Float16*)(&WT[off]) = (_Float16)Wa[i];
    }
    int wvi = tid >> 6, lane = tid & 63, ln = lane & 31, hi = lane >> 5;
    int rbase = blockIdx.x * 256 + wvi * 64;

    half8 af[2][4];
#pragma unroll
    for (int rt = 0; rt < 2; rt++)
#pragma unroll
        for (int kc = 0; kc < 4; kc++)
            af[rt][kc] = *(const half8*)(X + (size_t)(rbase + rt*32 + ln) * 64 + kc*16 + 8*hi);
    __syncthreads();

    half8 bf[2][4];
#pragma unroll
    for (int ct = 0; ct < 2; ct++)
#pragma unroll
        for (int kc = 0; kc < 4; kc++) {
            int e = ct * 32 + ln;
            int off = ((e * 64 + kc * 16 + 8 * hi) * 2) ^ ((e & 7) << 4);
            bf[ct][kc] = *(const half8*)(&WT[off]);
        }

    f32x16 acc[2][2];
#pragma unroll
    for (int rt = 0; rt < 2; rt++)
#pragma unroll
        for (int ct = 0; ct < 2; ct++) {
#pragma unroll
            for (int r = 0; r < 16; r++) acc[rt][ct][r] = 0.f;
#pragma unroll
            for (int kc = 0; kc < 4; kc++)
                acc[rt][ct] = __builtin_amdgcn_mfma_f32_32x32x16_f16(
                    af[rt][kc], bf[ct][kc], acc[rt][ct], 0, 0, 0);
        }

#pragma unroll
    for (int ct = 0; ct < 2; ct++) {
        float bv_ = ba[ct * 32 + ln];
        float s = 0.f, q = 0.f;
#pragma unroll
        for (int rt = 0; rt < 2; rt++)
#pragma unroll
            for (int r = 0; r < 16; r++) {
                float v = acc[rt][ct][r] + bv_;
                s += v; q += v * v;
                int row = rbase + rt*32 + (r & 3) + 8*(r >> 2) + 4*hi;
                Ya[(size_t)row * 64 + ct*32 + ln] = (_Float16)v;
            }
        s += __shfl_xor(s, 32, 64);
        q += __shfl_xor(q, 32, 64);
        if (lane < 32) {
            atomicAdd(&sta[ct*32 + ln], s);
            atomicAdd(&sta[64 + ct*32 + ln], q);
        }
    }
}

// ---------------------------------------------------------------------------
// MFMA attention, 512 thr / 8 waves per block, one block per (head, b*T+t).
// BN coefs computed in-block from raw stats (finalize fused). Q loaded
// directly from global in the strip loop (no QL staging). Softmax shift -12
// folded into the QK^T MFMA's C operand. V column 8 = ones -> denominator.
// ---------------------------------------------------------------------------
__global__ __launch_bounds__(512) void attn_mfma(
        const _Float16* __restrict__ Yq, const _Float16* __restrict__ Yk,
        const _Float16* __restrict__ Yv, const float* __restrict__ mask,
        const float* __restrict__ stats,
        const float* __restrict__ gq, const float* __restrict__ betaq,
        const float* __restrict__ gk, const float* __restrict__ betak,
        const float* __restrict__ gv, const float* __restrict__ betav,
        _Float16* __restrict__ O) {
    __shared__ __align__(16) _Float16 KL[512 * 8];      // 8 KB row-major [m][c]
    __shared__ __align__(16) _Float16 VS[64 * 9 * 8];   // 9 KB [m/8][c(0..8)][m%8]
    __shared__ float CF[384];                           // {q,k,v} x {a[64], b[64]}

    int p = blockIdx.x;
    int h = p / 96;              // B*T = 96
    int bt = p - h * 96;
    int row0 = bt * 512;
    int co = h * 8;
    int tid = threadIdx.x;

    // fused finalize: coefs from raw sums
    if (tid < 192) {
        int s = tid >> 6, c = tid & 63;
        const float* g  = s == 0 ? gq : (s == 1 ? gk : gv);
        const float* be = s == 0 ? betaq : (s == 1 ? betak : betav);
        const float* stp = stats + s * 128;
        float inv = 1.f / (float)RTOT;
        float mean = stp[c] * inv;
        float var  = stp[64 + c] * inv - mean * mean;
        float a = g[c] * rsqrtf(var + EPSF);
        CF[s * 128 + c] = a;
        CF[s * 128 + 64 + c] = be[c] - mean * a;
    }
    __syncthreads();

    // stage K (row-major) and V (chunk-interleaved), 1 row per thread
    {
        int m = tid;
        size_t base = (size_t)(row0 + m) * 64 + co;
        half8 yk = *(const half8*)(Yk + base);
        half8 yv = *(const half8*)(Yv + base);
        half8 kv;
        int ch = m >> 3, ii = m & 7;
#pragma unroll
        for (int c = 0; c < 8; c++) {
            kv[c] = (_Float16)fmaxf(CF[128 + co + c] * (float)yk[c] + CF[192 + co + c], 0.f);
            VS[ch * 72 + c * 8 + ii] =
                (_Float16)fmaxf(CF[256 + co + c] * (float)yv[c] + CF[320 + co + c], 0.f);
        }
        *(half8*)&KL[m * 8] = kv;
    }
    if (tid < 64) {
        half8 one8;
#pragma unroll
        for (int i = 0; i < 8; i++) one8[i] = (_Float16)1.0f;
        *(half8*)&VS[tid * 72 + 64] = one8;
    }
    __syncthreads();

    int wv = tid >> 6;           // 0..7
    int lane = tid & 63;
    int ln = lane & 31;
    int hi = lane >> 5;

    const float SC = 0.35355339059327373f * 1.4426950408889634f; // 1/sqrt(8)*log2(e)

    f32x16 zacc, m12;
#pragma unroll
    for (int r = 0; r < 16; r++) { zacc[r] = 0.f; m12[r] = -12.f; }
    half8 hzero;
#pragma unroll
    for (int i = 0; i < 8; i++) hzero[i] = (_Float16)0.f;

    // 16 query-strips of 32 rows; wave wv handles strips wv and wv+8
    for (int si = wv; si < 16; si += 8) {
        int n0 = si * 32;
        half8 qf = hzero;
        if (!hi) {
            size_t base = (size_t)(row0 + n0 + ln) * 64 + co;
            half8 y = *(const half8*)(Yq + base);
            const float4* mr = (const float4*)(mask + base);
            float4 m0 = mr[0], m1 = mr[1];
            float msum = m0.x+m0.y+m0.z+m0.w + m1.x+m1.y+m1.z+m1.w;
            float zm = (msum == 0.f) ? 0.f : SC;
#pragma unroll
            for (int c = 0; c < 8; c++)
                qf[c] = (_Float16)(fmaxf(CF[co + c] * (float)y[c] + CF[64 + co + c], 0.f) * zm);
        }
        f32x16 acc = zacc;

#pragma unroll 4
        for (int t = 0; t < 16; t++) {
            half8 kf = hzero;
            if (!hi) kf = *(const half8*)&KL[(t * 32 + ln) * 8];
            f32x16 sv = __builtin_amdgcn_mfma_f32_32x32x16_f16(kf, qf, m12, 0, 0, 0);
            float pe[16];
#pragma unroll
            for (int r = 0; r < 16; r++)
                pe[r] = __builtin_amdgcn_exp2f(sv[r]);
#pragma unroll
            for (int ks = 0; ks < 2; ks++) {
                unsigned int x1 = bcu(cvt2h(pe[8*ks+0], pe[8*ks+1]));
                unsigned int x2 = bcu(cvt2h(pe[8*ks+2], pe[8*ks+3]));
                unsigned int y1 = bcu(cvt2h(pe[8*ks+4], pe[8*ks+5]));
                unsigned int y2 = bcu(cvt2h(pe[8*ks+6], pe[8*ks+7]));
                swap32(x1, y1, hi);
                swap32(x2, y2, hi);
                uint4 pw = make_uint4(x1, x2, y1, y2);
                half8 pa = __builtin_bit_cast(half8, pw);
                int chunk = t * 4 + ks * 2 + hi;
                half8 vf = hzero;
                if (ln <= 8) vf = *(const half8*)&VS[chunk * 72 + ln * 8];
                acc = __builtin_amdgcn_mfma_f32_32x32x16_f16(pa, vf, acc, 0, 0, 0);
            }
        }

        // epilogue: c=8 lane of acc holds the softmax denominator
#pragma unroll
        for (int r = 0; r < 16; r++) {
            float av = acc[r];
            float den = __shfl(av, 8 + 32 * hi, 64);
            float ov = av * __builtin_amdgcn_rcpf(den);
            if (ln < 8) {
                int nrow = n0 + (r & 3) + 8 * (r >> 2) + 4 * hi;
                O[(size_t)(row0 + nrow) * 64 + co + ln] = (_Float16)ov;
            }
        }
    }
}

// out = relu(a*y + b) from f16 Y; finalize fused (coefs from raw stats)
__global__ __launch_bounds__(256) void norm_relu16(const _Float16* __restrict__ Y,
                                                   const float* __restrict__ st,
                                                   const float* __restrict__ g,
                                                   const float* __restrict__ be,
                                                   float* __restrict__ out) {
    __shared__ float CF[128];
    int tid = threadIdx.x;
    if (tid < 64) {
        float inv = 1.f / (float)RTOT;
        float mean = st[tid] * inv;
        float var  = st[64 + tid] * inv - mean * mean;
        float a = g[tid] * rsqrtf(var + EPSF);
        CF[tid] = a;
        CF[64 + tid] = be[tid] - mean * a;
    }
    __syncthreads();
    int i = blockIdx.x * 256 + tid;
    half8 y = ((const half8*)Y)[i];
    int cb = (i & 7) * 8;
    float4 o0, o1;
    o0.x = fmaxf(CF[cb+0]*(float)y[0] + CF[64+cb+0], 0.f);
    o0.y = fmaxf(CF[cb+1]*(float)y[1] + CF[64+cb+1], 0.f);
    o0.z = fmaxf(CF[cb+2]*(float)y[2] + CF[64+cb+2], 0.f);
    o0.w = fmaxf(CF[cb+3]*(float)y[3] + CF[64+cb+3], 0.f);
    o1.x = fmaxf(CF[cb+4]*(float)y[4] + CF[64+cb+4], 0.f);
    o1.y = fmaxf(CF[cb+5]*(float)y[5] + CF[64+cb+5], 0.f);
    o1.z = fmaxf(CF[cb+6]*(float)y[6] + CF[64+cb+6], 0.f);
    o1.w = fmaxf(CF[cb+7]*(float)y[7] + CF[64+cb+7], 0.f);
    ((float4*)out)[2*i]   = o0;
    ((float4*)out)[2*i+1] = o1;
}

extern "C" void kernel_launch(void* const* d_in, const int* in_sizes, int n_in,
                              void* d_out, int out_size, void* d_ws, size_t ws_size,
                              hipStream_t stream) {
    const float* Q    = (const float*)d_in[0];
    const float* Kin  = (const float*)d_in[1];
    const float* mask = (const float*)d_in[2];
    const float* Wq = (const float*)d_in[4];
    const float* bq = (const float*)d_in[5];
    const float* gq = (const float*)d_in[6];
    const float* betaq = (const float*)d_in[7];
    const float* Wk = (const float*)d_in[8];
    const float* bk = (const float*)d_in[9];
    const float* gk = (const float*)d_in[10];
    const float* betak = (const float*)d_in[11];
    const float* Wv = (const float*)d_in[12];
    const float* bv = (const float*)d_in[13];
    const float* gv = (const float*)d_in[14];
    const float* betav = (const float*)d_in[15];
    const float* Wo = (const float*)d_in[16];
    const float* bo = (const float*)d_in[17];
    const float* go = (const float*)d_in[18];
    const float* betao = (const float*)d_in[19];

    const size_t TSZ = (size_t)RTOT * 64;
    _Float16* Yq = (_Float16*)d_ws;
    _Float16* Yk = Yq + TSZ;
    _Float16* Yv = Yk + TSZ;
    _Float16* Ob = Yv + TSZ;
    _Float16* Yo = Ob + TSZ;
    float* stats = (float*)(Yo + TSZ);   // 512 floats (4 x {sum64, ssq64})

    (void)hipMemsetAsync(stats, 0, 512 * sizeof(float), stream);

    dim3 gqkv(192, 2);
    gemm_qkv<<<gqkv, 256, 0, stream>>>(Q, Kin, Wq, bq, Wk, bk, Wv, bv,
                                       Yq, Yk, Yv, stats);

    attn_mfma<<<768, 512, 0, stream>>>(Yq, Yk, Yv, mask, stats,
                                       gq, betaq, gk, betak, gv, betav, Ob);

    gemm_o<<<192, 256, 0, stream>>>(Ob, Wo, bo, Yo, stats + 384);

    norm_relu16<<<1536, 256, 0, stream>>>(Yo, stats + 384, go, betao, (float*)d_out);
}

// Round 7
// 114.500 us; speedup vs baseline: 2.8088x; 1.0050x over previous
//
#include <hip/hip_runtime.h>
#include <hip/hip_bf16.h>
#include <hip/hip_cooperative_groups.h>

#define RTOT 49152
#define EPSF 1e-5f

typedef _Float16 h2 __attribute__((ext_vector_type(2)));
typedef _Float16 half8 __attribute__((ext_vector_type(8)));
typedef float f32x16 __attribute__((ext_vector_type(16)));

__device__ __forceinline__ h2 cvt2h(float a, float b) {
    return __builtin_bit_cast(h2, __builtin_amdgcn_cvt_pkrtz(a, b));
}
__device__ __forceinline__ unsigned int bcu(h2 v) { return __builtin_bit_cast(unsigned int, v); }

// exchange: x's hi-32-lane half <-> y's lo-32-lane half
__device__ __forceinline__ void swap32(unsigned int& x, unsigned int& y, int hi) {
#if __has_builtin(__builtin_amdgcn_permlane32_swap)
    auto r = __builtin_amdgcn_permlane32_swap(x, y, false, false);
    x = r[0]; y = r[1];
#else
    unsigned int xs = (unsigned int)__shfl_xor((int)x, 32, 64);
    unsigned int ys = (unsigned int)__shfl_xor((int)y, 32, 64);
    unsigned int nx = hi ? ys : x;
    unsigned int ny = hi ? y : xs;
    x = nx; y = ny;
#endif
}

// ---------------------------------------------------------------------------
// QKV projection, grid (192, 3): y = 0/1/2 -> Q/K/V (one output per block,
// balanced). Stats: shfl -> LDS atomics -> 128 global atomics per block.
// Fragment layout (verified R4-R6): A/B lane&31 = M/N idx, lane>>5 = k-half;
// D row=(r&3)+8(r>>2)+4hi, col=lane&31.
// ---------------------------------------------------------------------------
__global__ __launch_bounds__(256) void gemm_qkv(
        const float* __restrict__ Qin, const float* __restrict__ Kin,
        const float* __restrict__ Wq, const float* __restrict__ bq,
        const float* __restrict__ Wk, const float* __restrict__ bk,
        const float* __restrict__ Wv, const float* __restrict__ bv,
        _Float16* __restrict__ Yq, _Float16* __restrict__ Yk,
        _Float16* __restrict__ Yv, float* __restrict__ stats) {
    __shared__ char WT[8192];
    __shared__ float red[128];
    int tid = threadIdx.x;
    int which = blockIdx.y;
    const float* X    = which ? Kin : Qin;
    const float* W    = which == 0 ? Wq : (which == 1 ? Wk : Wv);
    const float* bias = which == 0 ? bq : (which == 1 ? bk : bv);
    _Float16* Y       = which == 0 ? Yq : (which == 1 ? Yk : Yv);
    float* st = stats + which * 128;

    for (int i = tid; i < 4096; i += 256) {
        int d = i >> 6, e = i & 63;
        int off = ((e * 64 + d) * 2) ^ ((e & 7) << 4);
        *(_Float16*)(&WT[off]) = (_Float16)W[i];
    }
    if (tid < 128) red[tid] = 0.f;

    int wvi = tid >> 6, lane = tid & 63, ln = lane & 31, hi = lane >> 5;
    int rbase = blockIdx.x * 256 + wvi * 64;

    half8 af[2][4];
#pragma unroll
    for (int rt = 0; rt < 2; rt++)
#pragma unroll
        for (int kc = 0; kc < 4; kc++) {
            const float4* p = (const float4*)(X + (size_t)(rbase + rt*32 + ln) * 64 + kc*16 + 8*hi);
            float4 x = p[0], y = p[1];
            uint4 u = make_uint4(bcu(cvt2h(x.x, x.y)), bcu(cvt2h(x.z, x.w)),
                                 bcu(cvt2h(y.x, y.y)), bcu(cvt2h(y.z, y.w)));
            af[rt][kc] = __builtin_bit_cast(half8, u);
        }
    __syncthreads();

    half8 bf[2][4];
#pragma unroll
    for (int ct = 0; ct < 2; ct++)
#pragma unroll
        for (int kc = 0; kc < 4; kc++) {
            int e = ct * 32 + ln;
            int off = ((e * 64 + kc * 16 + 8 * hi) * 2) ^ ((e & 7) << 4);
            bf[ct][kc] = *(const half8*)(&WT[off]);
        }

    f32x16 acc[2][2];
#pragma unroll
    for (int rt = 0; rt < 2; rt++)
#pragma unroll
        for (int ct = 0; ct < 2; ct++) {
#pragma unroll
            for (int r = 0; r < 16; r++) acc[rt][ct][r] = 0.f;
#pragma unroll
            for (int kc = 0; kc < 4; kc++)
                acc[rt][ct] = __builtin_amdgcn_mfma_f32_32x32x16_f16(
                    af[rt][kc], bf[ct][kc], acc[rt][ct], 0, 0, 0);
        }

#pragma unroll
    for (int ct = 0; ct < 2; ct++) {
        float bv_ = bias[ct * 32 + ln];
        float s = 0.f, q = 0.f;
#pragma unroll
        for (int rt = 0; rt < 2; rt++)
#pragma unroll
            for (int r = 0; r < 16; r++) {
                float v = acc[rt][ct][r] + bv_;
                s += v; q += v * v;
                int row = rbase + rt*32 + (r & 3) + 8*(r >> 2) + 4*hi;
                Y[(size_t)row * 64 + ct*32 + ln] = (_Float16)v;
            }
        s += __shfl_xor(s, 32, 64);
        q += __shfl_xor(q, 32, 64);
        if (lane < 32) {
            atomicAdd(&red[ct*32 + ln], s);
            atomicAdd(&red[64 + ct*32 + ln], q);
        }
    }
    __syncthreads();
    if (tid < 128) atomicAdd(&st[tid], red[tid]);
}

// ---------------------------------------------------------------------------
// MFMA attention, 512 thr / 8 waves, grid 1536 = 2 blocks per (head, bt):
// block bid handles problem bid>>1, strips (bid&1)*8 + wave (one strip/wave).
// BN coefs fused from raw stats; Q direct from global; shift -12 in MFMA C;
// V column 8 = ones -> softmax denominator.
// ---------------------------------------------------------------------------
__global__ __launch_bounds__(512) void attn_mfma(
        const _Float16* __restrict__ Yq, const _Float16* __restrict__ Yk,
        const _Float16* __restrict__ Yv, const float* __restrict__ mask,
        const float* __restrict__ stats,
        const float* __restrict__ gq, const float* __restrict__ betaq,
        const float* __restrict__ gk, const float* __restrict__ betak,
        const float* __restrict__ gv, const float* __restrict__ betav,
        _Float16* __restrict__ O) {
    __shared__ __align__(16) _Float16 KL[512 * 8];      // 8 KB row-major [m][c]
    __shared__ __align__(16) _Float16 VS[64 * 9 * 8];   // 9 KB [m/8][c(0..8)][m%8]
    __shared__ float CF[384];                           // {q,k,v} x {a[64], b[64]}

    int bid = blockIdx.x;
    int p = bid >> 1;
    int half_ = bid & 1;
    int h = p / 96;              // B*T = 96
    int bt = p - h * 96;
    int row0 = bt * 512;
    int co = h * 8;
    int tid = threadIdx.x;

    if (tid < 192) {
        int s = tid >> 6, c = tid & 63;
        const float* g  = s == 0 ? gq : (s == 1 ? gk : gv);
        const float* be = s == 0 ? betaq : (s == 1 ? betak : betav);
        const float* stp = stats + s * 128;
        float inv = 1.f / (float)RTOT;
        float mean = stp[c] * inv;
        float var  = stp[64 + c] * inv - mean * mean;
        float a = g[c] * rsqrtf(var + EPSF);
        CF[s * 128 + c] = a;
        CF[s * 128 + 64 + c] = be[c] - mean * a;
    }
    __syncthreads();

    // stage K (row-major) and V (chunk-interleaved), 1 row per thread
    {
        int m = tid;
        size_t base = (size_t)(row0 + m) * 64 + co;
        half8 yk = *(const half8*)(Yk + base);
        half8 yv = *(const half8*)(Yv + base);
        half8 kv;
        int ch = m >> 3, ii = m & 7;
#pragma unroll
        for (int c = 0; c < 8; c++) {
            kv[c] = (_Float16)fmaxf(CF[128 + co + c] * (float)yk[c] + CF[192 + co + c], 0.f);
            VS[ch * 72 + c * 8 + ii] =
                (_Float16)fmaxf(CF[256 + co + c] * (float)yv[c] + CF[320 + co + c], 0.f);
        }
        *(half8*)&KL[m * 8] = kv;
    }
    if (tid < 64) {
        half8 one8;
#pragma unroll
        for (int i = 0; i < 8; i++) one8[i] = (_Float16)1.0f;
        *(half8*)&VS[tid * 72 + 64] = one8;
    }
    __syncthreads();

    int wv = tid >> 6;           // 0..7
    int lane = tid & 63;
    int ln = lane & 31;
    int hi = lane >> 5;

    const float SC = 0.35355339059327373f * 1.4426950408889634f; // 1/sqrt(8)*log2(e)

    f32x16 zacc, m12;
#pragma unroll
    for (int r = 0; r < 16; r++) { zacc[r] = 0.f; m12[r] = -12.f; }
    half8 hzero;
#pragma unroll
    for (int i = 0; i < 8; i++) hzero[i] = (_Float16)0.f;

    // one 32-row query strip per wave
    {
        int si = half_ * 8 + wv;
        int n0 = si * 32;
        half8 qf = hzero;
        if (!hi) {
            size_t base = (size_t)(row0 + n0 + ln) * 64 + co;
            half8 y = *(const half8*)(Yq + base);
            const float4* mr = (const float4*)(mask + base);
            float4 m0 = mr[0], m1 = mr[1];
            float msum = m0.x+m0.y+m0.z+m0.w + m1.x+m1.y+m1.z+m1.w;
            float zm = (msum == 0.f) ? 0.f : SC;
#pragma unroll
            for (int c = 0; c < 8; c++)
                qf[c] = (_Float16)(fmaxf(CF[co + c] * (float)y[c] + CF[64 + co + c], 0.f) * zm);
        }
        f32x16 acc = zacc;

#pragma unroll 4
        for (int t = 0; t < 16; t++) {
            half8 kf = hzero;
            if (!hi) kf = *(const half8*)&KL[(t * 32 + ln) * 8];
            f32x16 sv = __builtin_amdgcn_mfma_f32_32x32x16_f16(kf, qf, m12, 0, 0, 0);
            float pe[16];
#pragma unroll
            for (int r = 0; r < 16; r++)
                pe[r] = __builtin_amdgcn_exp2f(sv[r]);
#pragma unroll
            for (int ks = 0; ks < 2; ks++) {
                unsigned int x1 = bcu(cvt2h(pe[8*ks+0], pe[8*ks+1]));
                unsigned int x2 = bcu(cvt2h(pe[8*ks+2], pe[8*ks+3]));
                unsigned int y1 = bcu(cvt2h(pe[8*ks+4], pe[8*ks+5]));
                unsigned int y2 = bcu(cvt2h(pe[8*ks+6], pe[8*ks+7]));
                swap32(x1, y1, hi);
                swap32(x2, y2, hi);
                uint4 pw = make_uint4(x1, x2, y1, y2);
                half8 pa = __builtin_bit_cast(half8, pw);
                int chunk = t * 4 + ks * 2 + hi;
                half8 vf = hzero;
                if (ln <= 8) vf = *(const half8*)&VS[chunk * 72 + ln * 8];
                acc = __builtin_amdgcn_mfma_f32_32x32x16_f16(pa, vf, acc, 0, 0, 0);
            }
        }

        // epilogue: c=8 lane of acc holds the softmax denominator
#pragma unroll
        for (int r = 0; r < 16; r++) {
            float av = acc[r];
            float den = __shfl(av, 8 + 32 * hi, 64);
            float ov = av * __builtin_amdgcn_rcpf(den);
            if (ln < 8) {
                int nrow = n0 + (r & 3) + 8 * (r >> 2) + 4 * hi;
                O[(size_t)(row0 + nrow) * 64 + co + ln] = (_Float16)ov;
            }
        }
    }
}

// ---------------------------------------------------------------------------
// Cooperative: O-projection GEMM + stats + grid.sync + BN-ReLU -> d_out.
// 192 blocks x 256 thr (co-resident on 256 CUs). Accumulators stay in
// registers across the sync; Yo buffer eliminated.
// ---------------------------------------------------------------------------
__global__ __launch_bounds__(256) void gemm_o_norm(
        const _Float16* __restrict__ X,
        const float* __restrict__ Wo, const float* __restrict__ bo,
        const float* __restrict__ go, const float* __restrict__ betao,
        float* __restrict__ st, float* __restrict__ out) {
    __shared__ char WT[8192];
    __shared__ float red[128];
    __shared__ float CF[128];
    int tid = threadIdx.x;
    for (int i = tid; i < 4096; i += 256) {
        int d = i >> 6, e = i & 63;
        int off = ((e * 64 + d) * 2) ^ ((e & 7) << 4);
        *(_Float16*)(&WT[off]) = (_Float16)Wo[i];
    }
    if (tid < 128) red[tid] = 0.f;

    int wvi = tid >> 6, lane = tid & 63, ln = lane & 31, hi = lane >> 5;
    int rbase = blockIdx.x * 256 + wvi * 64;

    half8 af[2][4];
#pragma unroll
    for (int rt = 0; rt < 2; rt++)
#pragma unroll
        for (int kc = 0; kc < 4; kc++)
            af[rt][kc] = *(const half8*)(X + (size_t)(rbase + rt*32 + ln) * 64 + kc*16 + 8*hi);
    __syncthreads();

    half8 bf[2][4];
#pragma unroll
    for (int ct = 0; ct < 2; ct++)
#pragma unroll
        for (int kc = 0; kc < 4; kc++) {
            int e = ct * 32 + ln;
            int off = ((e * 64 + kc * 16 + 8 * hi) * 2) ^ ((e & 7) << 4);
            bf[ct][kc] = *(const half8*)(&WT[off]);
        }

    f32x16 acc[2][2];
#pragma unroll
    for (int rt = 0; rt < 2; rt++)
#pragma unroll
        for (int ct = 0; ct < 2; ct++) {
#pragma unroll
            for (int r = 0; r < 16; r++) acc[rt][ct][r] = 0.f;
#pragma unroll
            for (int kc = 0; kc < 4; kc++)
                acc[rt][ct] = __builtin_amdgcn_mfma_f32_32x32x16_f16(
                    af[rt][kc], bf[ct][kc], acc[rt][ct], 0, 0, 0);
        }

#pragma unroll
    for (int ct = 0; ct < 2; ct++) {
        float bv_ = bo[ct * 32 + ln];
        float s = 0.f, q = 0.f;
#pragma unroll
        for (int rt = 0; rt < 2; rt++)
#pragma unroll
            for (int r = 0; r < 16; r++) {
                float v = acc[rt][ct][r] + bv_;
                acc[rt][ct][r] = v;
                s += v; q += v * v;
            }
        s += __shfl_xor(s, 32, 64);
        q += __shfl_xor(q, 32, 64);
        if (lane < 32) {
            atomicAdd(&red[ct*32 + ln], s);
            atomicAdd(&red[64 + ct*32 + ln], q);
        }
    }
    __syncthreads();
    if (tid < 128) atomicAdd(&st[tid], red[tid]);

    __threadfence();
    cooperative_groups::this_grid().sync();

    if (tid < 64) {
        float inv = 1.f / (float)RTOT;
        float mean = st[tid] * inv;
        float var  = st[64 + tid] * inv - mean * mean;
        float a = go[tid] * rsqrtf(var + EPSF);
        CF[tid] = a;
        CF[64 + tid] = betao[tid] - mean * a;
    }
    __syncthreads();

#pragma unroll
    for (int ct = 0; ct < 2; ct++) {
        int c = ct * 32 + ln;
        float a = CF[c], b = CF[64 + c];
#pragma unroll
        for (int rt = 0; rt < 2; rt++)
#pragma unroll
            for (int r = 0; r < 16; r++) {
                int row = rbase + rt*32 + (r & 3) + 8*(r >> 2) + 4*hi;
                out[(size_t)row * 64 + c] = fmaxf(a * acc[rt][ct][r] + b, 0.f);
            }
    }
}

extern "C" void kernel_launch(void* const* d_in, const int* in_sizes, int n_in,
                              void* d_out, int out_size, void* d_ws, size_t ws_size,
                              hipStream_t stream) {
    const float* Q    = (const float*)d_in[0];
    const float* Kin  = (const float*)d_in[1];
    const float* mask = (const float*)d_in[2];
    const float* Wq = (const float*)d_in[4];
    const float* bq = (const float*)d_in[5];
    const float* gq = (const float*)d_in[6];
    const float* betaq = (const float*)d_in[7];
    const float* Wk = (const float*)d_in[8];
    const float* bk = (const float*)d_in[9];
    const float* gk = (const float*)d_in[10];
    const float* betak = (const float*)d_in[11];
    const float* Wv = (const float*)d_in[12];
    const float* bv = (const float*)d_in[13];
    const float* gv = (const float*)d_in[14];
    const float* betav = (const float*)d_in[15];
    const float* Wo = (const float*)d_in[16];
    const float* bo = (const float*)d_in[17];
    const float* go = (const float*)d_in[18];
    const float* betao = (const float*)d_in[19];

    const size_t TSZ = (size_t)RTOT * 64;
    _Float16* Yq = (_Float16*)d_ws;
    _Float16* Yk = Yq + TSZ;
    _Float16* Yv = Yk + TSZ;
    _Float16* Ob = Yv + TSZ;
    float* stats = (float*)(Ob + TSZ);   // 512 floats (4 x {sum64, ssq64})

    (void)hipMemsetAsync(stats, 0, 512 * sizeof(float), stream);

    dim3 gqkv(192, 3);
    gemm_qkv<<<gqkv, 256, 0, stream>>>(Q, Kin, Wq, bq, Wk, bk, Wv, bv,
                                       Yq, Yk, Yv, stats);

    attn_mfma<<<1536, 512, 0, stream>>>(Yq, Yk, Yv, mask, stats,
                                        gq, betaq, gk, betak, gv, betav, Ob);

    {
        const _Float16* Xo = Ob;
        float* st4 = stats + 384;
        float* outp = (float*)d_out;
        void* args[] = { (void*)&Xo, (void*)&Wo, (void*)&bo,
                         (void*)&go, (void*)&betao, (void*)&st4, (void*)&outp };
        (void)hipLaunchCooperativeKernel(reinterpret_cast<void*>(&gemm_o_norm),
                                         dim3(192), dim3(256), args, 0, stream);
    }
}

// Round 8
// 111.639 us; speedup vs baseline: 2.8808x; 1.0256x over previous
//
#include <hip/hip_runtime.h>
#include <hip/hip_bf16.h>
#include <hip/hip_cooperative_groups.h>

#define RTOT 49152
#define EPSF 1e-5f
#define SCQ 0.5101062398836783f   // (1/sqrt(8)) * log2(e)

typedef _Float16 h2 __attribute__((ext_vector_type(2)));
typedef _Float16 half8 __attribute__((ext_vector_type(8)));
typedef float f32x16 __attribute__((ext_vector_type(16)));

__device__ __forceinline__ h2 cvt2h(float a, float b) {
    return __builtin_bit_cast(h2, __builtin_amdgcn_cvt_pkrtz(a, b));
}
__device__ __forceinline__ unsigned int bcu(h2 v) { return __builtin_bit_cast(unsigned int, v); }

__device__ __forceinline__ void swap32(unsigned int& x, unsigned int& y, int hi) {
#if __has_builtin(__builtin_amdgcn_permlane32_swap)
    auto r = __builtin_amdgcn_permlane32_swap(x, y, false, false);
    x = r[0]; y = r[1];
#else
    unsigned int xs = (unsigned int)__shfl_xor((int)x, 32, 64);
    unsigned int ys = (unsigned int)__shfl_xor((int)y, 32, 64);
    unsigned int nx = hi ? ys : x;
    unsigned int ny = hi ? y : xs;
    x = nx; y = ny;
#endif
}

// ---------------------------------------------------------------------------
// QKV projection, grid (192, 3): y = 0/1/2 -> Q/K/V. Output HEAD-MAJOR:
// Y[h][row][c] (h=cc>>3, c=cc&7) so attention stages contiguously.
// y==0 blocks also fold mask row-sums into zt[h][row] in {0, SCQ} (f16).
// Stats: shfl -> LDS atomics -> 128 global atomics per block.
// ---------------------------------------------------------------------------
__global__ __launch_bounds__(256) void gemm_qkv(
        const float* __restrict__ Qin, const float* __restrict__ Kin,
        const float* __restrict__ mask,
        const float* __restrict__ Wq, const float* __restrict__ bq,
        const float* __restrict__ Wk, const float* __restrict__ bk,
        const float* __restrict__ Wv, const float* __restrict__ bv,
        _Float16* __restrict__ Yq, _Float16* __restrict__ Yk,
        _Float16* __restrict__ Yv, _Float16* __restrict__ zt,
        float* __restrict__ stats) {
    __shared__ char WT[8192];
    __shared__ float red[128];
    int tid = threadIdx.x;
    int which = blockIdx.y;
    const float* X    = which ? Kin : Qin;
    const float* W    = which == 0 ? Wq : (which == 1 ? Wk : Wv);
    const float* bias = which == 0 ? bq : (which == 1 ? bk : bv);
    _Float16* Y       = which == 0 ? Yq : (which == 1 ? Yk : Yv);
    float* st = stats + which * 128;

    for (int i = tid; i < 4096; i += 256) {
        int d = i >> 6, e = i & 63;
        int off = ((e * 64 + d) * 2) ^ ((e & 7) << 4);
        *(_Float16*)(&WT[off]) = (_Float16)W[i];
    }
    if (tid < 128) red[tid] = 0.f;

    int wvi = tid >> 6, lane = tid & 63, ln = lane & 31, hi = lane >> 5;
    int rbase = blockIdx.x * 256 + wvi * 64;

    half8 af[2][4];
#pragma unroll
    for (int rt = 0; rt < 2; rt++)
#pragma unroll
        for (int kc = 0; kc < 4; kc++) {
            const float4* p = (const float4*)(X + (size_t)(rbase + rt*32 + ln) * 64 + kc*16 + 8*hi);
            float4 x = p[0], y = p[1];
            uint4 u = make_uint4(bcu(cvt2h(x.x, x.y)), bcu(cvt2h(x.z, x.w)),
                                 bcu(cvt2h(y.x, y.y)), bcu(cvt2h(y.z, y.w)));
            af[rt][kc] = __builtin_bit_cast(half8, u);
        }

    // mask row-sum table (Q blocks only): zt[h][row] = (sum of head chunk)==0 ? 0 : SCQ
    if (which == 0) {
        int row = blockIdx.x * 256 + tid;
        const float4* mr = (const float4*)(mask + (size_t)row * 64);
        float s[8];
#pragma unroll
        for (int h8 = 0; h8 < 8; h8++) s[h8] = 0.f;
#pragma unroll
        for (int i = 0; i < 16; i++) {
            float4 m = mr[i];
            s[i >> 1] += m.x + m.y + m.z + m.w;
        }
#pragma unroll
        for (int h8 = 0; h8 < 8; h8++)
            zt[(size_t)h8 * RTOT + row] = (_Float16)((s[h8] == 0.f) ? 0.f : SCQ);
    }
    __syncthreads();

    half8 bf[2][4];
#pragma unroll
    for (int ct = 0; ct < 2; ct++)
#pragma unroll
        for (int kc = 0; kc < 4; kc++) {
            int e = ct * 32 + ln;
            int off = ((e * 64 + kc * 16 + 8 * hi) * 2) ^ ((e & 7) << 4);
            bf[ct][kc] = *(const half8*)(&WT[off]);
        }

    f32x16 acc[2][2];
#pragma unroll
    for (int rt = 0; rt < 2; rt++)
#pragma unroll
        for (int ct = 0; ct < 2; ct++) {
#pragma unroll
            for (int r = 0; r < 16; r++) acc[rt][ct][r] = 0.f;
#pragma unroll
            for (int kc = 0; kc < 4; kc++)
                acc[rt][ct] = __builtin_amdgcn_mfma_f32_32x32x16_f16(
                    af[rt][kc], bf[ct][kc], acc[rt][ct], 0, 0, 0);
        }

#pragma unroll
    for (int ct = 0; ct < 2; ct++) {
        int cc = ct * 32 + ln;
        float bv_ = bias[cc];
        _Float16* Yh = Y + (size_t)(cc >> 3) * RTOT * 8 + (cc & 7);
        float s = 0.f, q = 0.f;
#pragma unroll
        for (int rt = 0; rt < 2; rt++)
#pragma unroll
            for (int r = 0; r < 16; r++) {
                float v = acc[rt][ct][r] + bv_;
                s += v; q += v * v;
                int row = rbase + rt*32 + (r & 3) + 8*(r >> 2) + 4*hi;
                Yh[(size_t)row * 8] = (_Float16)v;
            }
        s += __shfl_xor(s, 32, 64);
        q += __shfl_xor(q, 32, 64);
        if (lane < 32) {
            atomicAdd(&red[cc], s);
            atomicAdd(&red[64 + cc], q);
        }
    }
    __syncthreads();
    if (tid < 128) atomicAdd(&st[tid], red[tid]);
}

// ---------------------------------------------------------------------------
// MFMA attention, 512 thr / 8 waves. Grid 1536: p = bid mod 768,
// half = bid/768 (768 = 0 mod 8 -> pair-mates land on the same XCD for L2
// reuse of the duplicated K/V staging). One 32-row query strip per wave.
// Head-major Y in, head-major O out. zm from zt table (no mask reads).
// ---------------------------------------------------------------------------
__global__ __launch_bounds__(512) void attn_mfma(
        const _Float16* __restrict__ Yq, const _Float16* __restrict__ Yk,
        const _Float16* __restrict__ Yv, const _Float16* __restrict__ zt,
        const float* __restrict__ stats,
        const float* __restrict__ gq, const float* __restrict__ betaq,
        const float* __restrict__ gk, const float* __restrict__ betak,
        const float* __restrict__ gv, const float* __restrict__ betav,
        _Float16* __restrict__ O) {
    __shared__ __align__(16) _Float16 KL[512 * 8];      // 8 KB row-major [m][c]
    __shared__ __align__(16) _Float16 VS[64 * 9 * 8];   // 9 KB [m/8][c(0..8)][m%8]
    __shared__ float CF[384];                           // {q,k,v} x {a[64], b[64]}

    int bid = blockIdx.x;
    int p = (bid < 768) ? bid : bid - 768;
    int half_ = (bid < 768) ? 0 : 1;
    int h = p / 96;              // B*T = 96
    int bt = p - h * 96;
    int row0 = bt * 512;
    int co = h * 8;
    int tid = threadIdx.x;

    if (tid < 192) {
        int s = tid >> 6, c = tid & 63;
        const float* g  = s == 0 ? gq : (s == 1 ? gk : gv);
        const float* be = s == 0 ? betaq : (s == 1 ? betak : betav);
        const float* stp = stats + s * 128;
        float inv = 1.f / (float)RTOT;
        float mean = stp[c] * inv;
        float var  = stp[64 + c] * inv - mean * mean;
        float a = g[c] * rsqrtf(var + EPSF);
        CF[s * 128 + c] = a;
        CF[s * 128 + 64 + c] = be[c] - mean * a;
    }
    __syncthreads();

    const _Float16* Ykh = Yk + (size_t)h * RTOT * 8 + (size_t)row0 * 8;
    const _Float16* Yvh = Yv + (size_t)h * RTOT * 8 + (size_t)row0 * 8;
    const _Float16* Yqh = Yq + (size_t)h * RTOT * 8 + (size_t)row0 * 8;

    // stage K (row-major) and V (chunk-interleaved), 1 row per thread
    {
        int m = tid;
        half8 yk = *(const half8*)(Ykh + m * 8);
        half8 yv = *(const half8*)(Yvh + m * 8);
        half8 kv;
        int ch = m >> 3, ii = m & 7;
#pragma unroll
        for (int c = 0; c < 8; c++) {
            kv[c] = (_Float16)fmaxf(CF[128 + co + c] * (float)yk[c] + CF[192 + co + c], 0.f);
            VS[ch * 72 + c * 8 + ii] =
                (_Float16)fmaxf(CF[256 + co + c] * (float)yv[c] + CF[320 + co + c], 0.f);
        }
        *(half8*)&KL[m * 8] = kv;
    }
    if (tid < 64) {
        half8 one8;
#pragma unroll
        for (int i = 0; i < 8; i++) one8[i] = (_Float16)1.0f;
        *(half8*)&VS[tid * 72 + 64] = one8;
    }
    __syncthreads();

    int wv = tid >> 6;           // 0..7
    int lane = tid & 63;
    int ln = lane & 31;
    int hi = lane >> 5;

    f32x16 zacc, m12;
#pragma unroll
    for (int r = 0; r < 16; r++) { zacc[r] = 0.f; m12[r] = -12.f; }
    half8 hzero;
#pragma unroll
    for (int i = 0; i < 8; i++) hzero[i] = (_Float16)0.f;

    // one 32-row query strip per wave
    {
        int si = half_ * 8 + wv;
        int n0 = si * 32;
        half8 qf = hzero;
        if (!hi) {
            half8 y = *(const half8*)(Yqh + (n0 + ln) * 8);
            float zmv = (float)zt[(size_t)h * RTOT + row0 + n0 + ln];
#pragma unroll
            for (int c = 0; c < 8; c++)
                qf[c] = (_Float16)(fmaxf(CF[co + c] * (float)y[c] + CF[64 + co + c], 0.f) * zmv);
        }
        f32x16 acc = zacc;

#pragma unroll 4
        for (int t = 0; t < 16; t++) {
            half8 kf = hzero;
            if (!hi) kf = *(const half8*)&KL[(t * 32 + ln) * 8];
            f32x16 sv = __builtin_amdgcn_mfma_f32_32x32x16_f16(kf, qf, m12, 0, 0, 0);
            float pe[16];
#pragma unroll
            for (int r = 0; r < 16; r++)
                pe[r] = __builtin_amdgcn_exp2f(sv[r]);
#pragma unroll
            for (int ks = 0; ks < 2; ks++) {
                unsigned int x1 = bcu(cvt2h(pe[8*ks+0], pe[8*ks+1]));
                unsigned int x2 = bcu(cvt2h(pe[8*ks+2], pe[8*ks+3]));
                unsigned int y1 = bcu(cvt2h(pe[8*ks+4], pe[8*ks+5]));
                unsigned int y2 = bcu(cvt2h(pe[8*ks+6], pe[8*ks+7]));
                swap32(x1, y1, hi);
                swap32(x2, y2, hi);
                uint4 pw = make_uint4(x1, x2, y1, y2);
                half8 pa = __builtin_bit_cast(half8, pw);
                int chunk = t * 4 + ks * 2 + hi;
                half8 vf = hzero;
                if (ln <= 8) vf = *(const half8*)&VS[chunk * 72 + ln * 8];
                acc = __builtin_amdgcn_mfma_f32_32x32x16_f16(pa, vf, acc, 0, 0, 0);
            }
        }

        // epilogue: c=8 lane of acc holds the softmax denominator
        _Float16* Oh = O + (size_t)h * RTOT * 8 + (size_t)row0 * 8;
#pragma unroll
        for (int r = 0; r < 16; r++) {
            float av = acc[r];
            float den = __shfl(av, 8 + 32 * hi, 64);
            float ov = av * __builtin_amdgcn_rcpf(den);
            if (ln < 8) {
                int nrow = n0 + (r & 3) + 8 * (r >> 2) + 4 * hi;
                Oh[nrow * 8 + ln] = (_Float16)ov;
            }
        }
    }
}

// ---------------------------------------------------------------------------
// Cooperative: O-projection GEMM (head-major X) + stats + grid.sync + BN-ReLU
// -> d_out. 192 blocks x 256 thr. Accumulators live across the sync.
// ---------------------------------------------------------------------------
__global__ __launch_bounds__(256) void gemm_o_norm(
        const _Float16* __restrict__ X,
        const float* __restrict__ Wo, const float* __restrict__ bo,
        const float* __restrict__ go, const float* __restrict__ betao,
        float* __restrict__ st, float* __restrict__ out) {
    __shared__ char WT[8192];
    __shared__ float red[128];
    __shared__ float CF[128];
    int tid = threadIdx.x;
    for (int i = tid; i < 4096; i += 256) {
        int d = i >> 6, e = i & 63;
        int off = ((e * 64 + d) * 2) ^ ((e & 7) << 4);
        *(_Float16*)(&WT[off]) = (_Float16)Wo[i];
    }
    if (tid < 128) red[tid] = 0.f;

    int wvi = tid >> 6, lane = tid & 63, ln = lane & 31, hi = lane >> 5;
    int rbase = blockIdx.x * 256 + wvi * 64;

    half8 af[2][4];
#pragma unroll
    for (int rt = 0; rt < 2; rt++)
#pragma unroll
        for (int kc = 0; kc < 4; kc++)
            af[rt][kc] = *(const half8*)(X + ((size_t)(2*kc + hi) * RTOT + rbase + rt*32 + ln) * 8);
    __syncthreads();

    half8 bf[2][4];
#pragma unroll
    for (int ct = 0; ct < 2; ct++)
#pragma unroll
        for (int kc = 0; kc < 4; kc++) {
            int e = ct * 32 + ln;
            int off = ((e * 64 + kc * 16 + 8 * hi) * 2) ^ ((e & 7) << 4);
            bf[ct][kc] = *(const half8*)(&WT[off]);
        }

    f32x16 acc[2][2];
#pragma unroll
    for (int rt = 0; rt < 2; rt++)
#pragma unroll
        for (int ct = 0; ct < 2; ct++) {
#pragma unroll
            for (int r = 0; r < 16; r++) acc[rt][ct][r] = 0.f;
#pragma unroll
            for (int kc = 0; kc < 4; kc++)
                acc[rt][ct] = __builtin_amdgcn_mfma_f32_32x32x16_f16(
                    af[rt][kc], bf[ct][kc], acc[rt][ct], 0, 0, 0);
        }

#pragma unroll
    for (int ct = 0; ct < 2; ct++) {
        float bv_ = bo[ct * 32 + ln];
        float s = 0.f, q = 0.f;
#pragma unroll
        for (int rt = 0; rt < 2; rt++)
#pragma unroll
            for (int r = 0; r < 16; r++) {
                float v = acc[rt][ct][r] + bv_;
                acc[rt][ct][r] = v;
                s += v; q += v * v;
            }
        s += __shfl_xor(s, 32, 64);
        q += __shfl_xor(q, 32, 64);
        if (lane < 32) {
            atomicAdd(&red[ct*32 + ln], s);
            atomicAdd(&red[64 + ct*32 + ln], q);
        }
    }
    __syncthreads();
    if (tid < 128) atomicAdd(&st[tid], red[tid]);

    __threadfence();
    cooperative_groups::this_grid().sync();

    if (tid < 64) {
        float inv = 1.f / (float)RTOT;
        float mean = st[tid] * inv;
        float var  = st[64 + tid] * inv - mean * mean;
        float a = go[tid] * rsqrtf(var + EPSF);
        CF[tid] = a;
        CF[64 + tid] = betao[tid] - mean * a;
    }
    __syncthreads();

#pragma unroll
    for (int ct = 0; ct < 2; ct++) {
        int c = ct * 32 + ln;
        float a = CF[c], b = CF[64 + c];
#pragma unroll
        for (int rt = 0; rt < 2; rt++)
#pragma unroll
            for (int r = 0; r < 16; r++) {
                int row = rbase + rt*32 + (r & 3) + 8*(r >> 2) + 4*hi;
                out[(size_t)row * 64 + c] = fmaxf(a * acc[rt][ct][r] + b, 0.f);
            }
    }
}

extern "C" void kernel_launch(void* const* d_in, const int* in_sizes, int n_in,
                              void* d_out, int out_size, void* d_ws, size_t ws_size,
                              hipStream_t stream) {
    const float* Q    = (const float*)d_in[0];
    const float* Kin  = (const float*)d_in[1];
    const float* mask = (const float*)d_in[2];
    const float* Wq = (const float*)d_in[4];
    const float* bq = (const float*)d_in[5];
    const float* gq = (const float*)d_in[6];
    const float* betaq = (const float*)d_in[7];
    const float* Wk = (const float*)d_in[8];
    const float* bk = (const float*)d_in[9];
    const float* gk = (const float*)d_in[10];
    const float* betak = (const float*)d_in[11];
    const float* Wv = (const float*)d_in[12];
    const float* bv = (const float*)d_in[13];
    const float* gv = (const float*)d_in[14];
    const float* betav = (const float*)d_in[15];
    const float* Wo = (const float*)d_in[16];
    const float* bo = (const float*)d_in[17];
    const float* go = (const float*)d_in[18];
    const float* betao = (const float*)d_in[19];

    const size_t TSZ = (size_t)RTOT * 64;
    _Float16* Yq = (_Float16*)d_ws;
    _Float16* Yk = Yq + TSZ;
    _Float16* Yv = Yk + TSZ;
    _Float16* Ob = Yv + TSZ;
    _Float16* zt = Ob + TSZ;             // 8 * RTOT f16
    float* stats = (float*)(zt + (size_t)8 * RTOT);  // 512 floats

    (void)hipMemsetAsync(stats, 0, 512 * sizeof(float), stream);

    dim3 gqkv(192, 3);
    gemm_qkv<<<gqkv, 256, 0, stream>>>(Q, Kin, mask, Wq, bq, Wk, bk, Wv, bv,
                                       Yq, Yk, Yv, zt, stats);

    attn_mfma<<<1536, 512, 0, stream>>>(Yq, Yk, Yv, zt, stats,
                                        gq, betaq, gk, betak, gv, betav, Ob);

    {
        const _Float16* Xo = Ob;
        float* st4 = stats + 384;
        float* outp = (float*)d_out;
        void* args[] = { (void*)&Xo, (void*)&Wo, (void*)&bo,
                         (void*)&go, (void*)&betao, (void*)&st4, (void*)&outp };
        (void)hipLaunchCooperativeKernel(reinterpret_cast<void*>(&gemm_o_norm),
                                         dim3(192), dim3(256), args, 0, stream);
    }
}